// Round 7
// baseline (316.831 us; speedup 1.0000x reference)
//
#include <hip/hip_runtime.h>
#include <hip/hip_bf16.h>
#include <math.h>

#define B_ 2
#define S_ 2048
#define D_ 1024
#define H_ 16
#define HD 64
#define M_ (B_ * S_)     // 4096
#define N_QKV (3 * D_)   // 3072

typedef short short8 __attribute__((ext_vector_type(8)));
typedef float floatx4 __attribute__((ext_vector_type(4)));

// HW RNE f32->bf16 (compiler emits v_cvt_pk_bf16_f32)
static __device__ __forceinline__ unsigned short f2bf(float x) {
    __hip_bfloat16 h = __float2bfloat16(x);
    unsigned short u;
    __builtin_memcpy(&u, &h, sizeof(u));
    return u;
}
static __device__ __forceinline__ float bf2f(unsigned short b) {
    union { unsigned u; float f; } v; v.u = ((unsigned)b) << 16;
    return v.f;
}
// RNE split: x = hi + lo + eps, |eps| ~ 2^-17 |x|
static __device__ __forceinline__ void split2(float x, unsigned short& h, unsigned short& l) {
    h = f2bf(x);
    l = f2bf(x - bf2f(h));
}

// async global->LDS DMA, 16 B per lane (dest = wave-uniform base + lane*16)
static __device__ __forceinline__ void dma16(const void* g, void* l) {
    __builtin_amdgcn_global_load_lds(
        (const __attribute__((address_space(1))) unsigned int*)g,
        (__attribute__((address_space(3))) unsigned int*)l,
        16, 0, 0);
}

// ---------------------------------------------------------------------------
// prep_A: hs fp32 [4096][1024] -> Ahi/Alo bf16.
// ---------------------------------------------------------------------------
__global__ __launch_bounds__(256) void prep_A(
    const float* __restrict__ X,
    unsigned short* __restrict__ Ahi, unsigned short* __restrict__ Alo)
{
    const size_t i = ((size_t)blockIdx.x * 256 + threadIdx.x) * 8;
    float4 a = *(const float4*)(X + i);
    float4 b = *(const float4*)(X + i + 4);
    float xs[8] = {a.x, a.y, a.z, a.w, b.x, b.y, b.z, b.w};
    short8 h, l;
#pragma unroll
    for (int e = 0; e < 8; e++) {
        unsigned short hh, ll;
        split2(xs[e], hh, ll);
        h[e] = (short)hh; l[e] = (short)ll;
    }
    *(short8*)&Ahi[i] = h;
    *(short8*)&Alo[i] = l;
}

// ---------------------------------------------------------------------------
// prep_wT: W[K=1024][N] fp32 -> WT hi/lo bf16 [N][1024]. (verified)
// ---------------------------------------------------------------------------
__global__ __launch_bounds__(256) void prep_wT(
    const float* __restrict__ W, int N,
    unsigned short* __restrict__ Thi, unsigned short* __restrict__ Tlo)
{
    __shared__ float Ws[64][68];
    const int t  = threadIdx.x;
    const int n0 = blockIdx.x * 64, k0 = blockIdx.y * 64;
    {
        const int kl = t >> 4, nl = (t & 15) * 4;
        const float* src = W + (size_t)(k0 + kl) * N + n0 + nl;
#pragma unroll
        for (int g = 0; g < 4; g++)
            *(float4*)&Ws[kl + g * 16][nl] = *(const float4*)(src + (size_t)g * 16 * N);
    }
    __syncthreads();
    {
        const int nl = t >> 2, ks = (t & 3) * 16;
        short8 h0, h1, l0, l1;
#pragma unroll
        for (int j = 0; j < 8; j++) {
            unsigned short hh, ll;
            split2(Ws[ks + j][nl], hh, ll);
            h0[j] = (short)hh; l0[j] = (short)ll;
        }
#pragma unroll
        for (int j = 0; j < 8; j++) {
            unsigned short hh, ll;
            split2(Ws[ks + 8 + j][nl], hh, ll);
            h1[j] = (short)hh; l1[j] = (short)ll;
        }
        unsigned short* dh = Thi + (size_t)(n0 + nl) * D_ + k0 + ks;
        unsigned short* dl = Tlo + (size_t)(n0 + nl) * D_ + k0 + ks;
        *(short8*)dh = h0; *(short8*)(dh + 8) = h1;
        *(short8*)dl = l0; *(short8*)(dl + 8) = l1;
    }
}

// ---------------------------------------------------------------------------
// QKV GEMM (unchanged, measured ~107 us): m97 structure, 128x128 tile,
// single 32KB buffer, fully-DMA staging, zero K-loop VALU.
// ---------------------------------------------------------------------------
__global__ __launch_bounds__(256) void gemm_qkv(
    const unsigned short* __restrict__ Ahi, const unsigned short* __restrict__ Alo,
    const unsigned short* __restrict__ BThi, const unsigned short* __restrict__ BTlo,
    const float* __restrict__ bias,
    unsigned short* __restrict__ Qhi, unsigned short* __restrict__ Qlo,
    unsigned short* __restrict__ Khi, unsigned short* __restrict__ Klo,
    unsigned short* __restrict__ vThi, unsigned short* __restrict__ vTlo)
{
    __shared__ unsigned short sAh[128 * 32], sAl[128 * 32];
    __shared__ unsigned short sBh[128 * 32], sBl[128 * 32];   // 32 KB

    const int t    = threadIdx.x;
    const int m0   = blockIdx.y * 128, n0 = blockIdx.x * 128;
    const int lane = t & 63, wave = t >> 6;
    const int lm   = lane & 15, quad = lane >> 4;
    const int wm   = (wave >> 1) * 64, wn = (wave & 1) * 64;

    const int lrow = lane >> 2, lcol = (lane & 3) * 8;
    const unsigned short* gAh = Ahi + (size_t)(m0 + wave * 32 + lrow) * D_ + lcol;
    const unsigned short* gAl = Alo + (size_t)(m0 + wave * 32 + lrow) * D_ + lcol;
    const unsigned short* gBh = BThi + (size_t)(n0 + wave * 32 + lrow) * D_ + lcol;
    const unsigned short* gBl = BTlo + (size_t)(n0 + wave * 32 + lrow) * D_ + lcol;
    const int ldst = wave * 1024 + lane * 8;   // u16 dest (= base + lane*16B)

    floatx4 acc[4][4];
#pragma unroll
    for (int i = 0; i < 4; i++)
#pragma unroll
        for (int j = 0; j < 4; j++)
#pragma unroll
            for (int r = 0; r < 4; r++) acc[i][j][r] = 0.f;

    for (int k0 = 0; k0 < D_; k0 += 32) {
        __syncthreads();   // readers of previous tile done
        dma16(gAh + k0, &sAh[ldst]);
        dma16(gAh + (size_t)16 * D_ + k0, &sAh[ldst + 512]);
        dma16(gAl + k0, &sAl[ldst]);
        dma16(gAl + (size_t)16 * D_ + k0, &sAl[ldst + 512]);
        dma16(gBh + k0, &sBh[ldst]);
        dma16(gBh + (size_t)16 * D_ + k0, &sBh[ldst + 512]);
        dma16(gBl + k0, &sBl[ldst]);
        dma16(gBl + (size_t)16 * D_ + k0, &sBl[ldst + 512]);
        __syncthreads();   // staged (compiler drains vmcnt(0) here)

        short8 bhf[4], blf[4];
#pragma unroll
        for (int nb = 0; nb < 4; nb++) {
            const int r = wn + nb * 16 + lm;
            bhf[nb] = *(const short8*)&sBh[r * 32 + quad * 8];
            blf[nb] = *(const short8*)&sBl[r * 32 + quad * 8];
        }
#pragma unroll
        for (int mb = 0; mb < 4; mb++) {
            const int r = wm + mb * 16 + lm;
            short8 ah = *(const short8*)&sAh[r * 32 + quad * 8];
            short8 al = *(const short8*)&sAl[r * 32 + quad * 8];
#pragma unroll
            for (int nb = 0; nb < 4; nb++) {
                acc[mb][nb] = __builtin_amdgcn_mfma_f32_16x16x32_bf16(ah, bhf[nb], acc[mb][nb], 0, 0, 0);
                acc[mb][nb] = __builtin_amdgcn_mfma_f32_16x16x32_bf16(al, bhf[nb], acc[mb][nb], 0, 0, 0);
                acc[mb][nb] = __builtin_amdgcn_mfma_f32_16x16x32_bf16(ah, blf[nb], acc[mb][nb], 0, 0, 0);
            }
        }
    }

    const int nmode = n0 >> 10;
    if (nmode == 0) {
#pragma unroll
        for (int nb = 0; nb < 4; nb++) {
            const int c = n0 + wn + nb * 16 + lm;
            const float bv = bias[c];
#pragma unroll
            for (int mb = 0; mb < 4; mb++) {
                const int rowb = m0 + wm + mb * 16 + quad * 4;
#pragma unroll
                for (int r = 0; r < 4; r++) {
                    unsigned short hh, ll;
                    split2((acc[mb][nb][r] + bv) * 0.125f, hh, ll);
                    Qhi[(size_t)(rowb + r) * D_ + c] = hh;
                    Qlo[(size_t)(rowb + r) * D_ + c] = ll;
                }
            }
        }
    } else if (nmode == 1) {
#pragma unroll
        for (int nb = 0; nb < 4; nb++) {
            const int c = n0 + wn + nb * 16 + lm;
            const float bv = bias[c];
            const int cq = c - 1024;
#pragma unroll
            for (int mb = 0; mb < 4; mb++) {
                const int rowb = m0 + wm + mb * 16 + quad * 4;
#pragma unroll
                for (int r = 0; r < 4; r++) {
                    unsigned short hh, ll;
                    split2(acc[mb][nb][r] + bv, hh, ll);
                    Khi[(size_t)(rowb + r) * D_ + cq] = hh;
                    Klo[(size_t)(rowb + r) * D_ + cq] = ll;
                }
            }
        }
    } else {
#pragma unroll
        for (int nb = 0; nb < 4; nb++) {
            const int c = n0 + wn + nb * 16 + lm;
            const float bv = bias[c];
            const int cq = c - 2048;
            const int hh_ = cq >> 6, dd = cq & 63;
#pragma unroll
            for (int mb = 0; mb < 4; mb++) {
                const int rowb = m0 + wm + mb * 16 + quad * 4;
                const int bb = rowb >> 11, ss = rowb & 2047;
                unsigned short hv[4], lv[4];
#pragma unroll
                for (int r = 0; r < 4; r++)
                    split2(acc[mb][nb][r] + bv, hv[r], lv[r]);
                const size_t idx = ((size_t)((bb * 16 + hh_) * 64 + dd)) * S_ + ss;
                *(uint2*)&vThi[idx] = make_uint2((unsigned)hv[0] | ((unsigned)hv[1] << 16),
                                                 (unsigned)hv[2] | ((unsigned)hv[3] << 16));
                *(uint2*)&vTlo[idx] = make_uint2((unsigned)lv[0] | ((unsigned)lv[1] << 16),
                                                 (unsigned)lv[2] | ((unsigned)lv[3] << 16));
            }
        }
    }
}

// ---------------------------------------------------------------------------
// Proj GEMM, SPLIT-K x2 WITHOUT atomics: grid (8,32,2) = 512 blocks (2/CU),
// each runs the m97 128x128 DMA inner loop over K=512 (48 MFMA/wave/step,
// 4x the 64^2 density). kc=0 writes C+bias; kc=1 writes partial buffer
// (reuses dead Khi/Klo space). add_partial folds it in (no atomics).
// ---------------------------------------------------------------------------
__global__ __launch_bounds__(256) void gemm_out(
    const unsigned short* __restrict__ Ahi, const unsigned short* __restrict__ Alo,
    const unsigned short* __restrict__ BThi, const unsigned short* __restrict__ BTlo,
    const float* __restrict__ bias, float* __restrict__ C, float* __restrict__ P)
{
    __shared__ unsigned short sAh[128 * 32], sAl[128 * 32];
    __shared__ unsigned short sBh[128 * 32], sBl[128 * 32];   // 32 KB

    const int t     = threadIdx.x;
    const int m0    = blockIdx.y * 128, n0 = blockIdx.x * 128;
    const int kbase = blockIdx.z * 512;
    const int lane = t & 63, wave = t >> 6;
    const int lm   = lane & 15, quad = lane >> 4;
    const int wm   = (wave >> 1) * 64, wn = (wave & 1) * 64;

    const int lrow = lane >> 2, lcol = (lane & 3) * 8;
    const unsigned short* gAh = Ahi + (size_t)(m0 + wave * 32 + lrow) * D_ + lcol + kbase;
    const unsigned short* gAl = Alo + (size_t)(m0 + wave * 32 + lrow) * D_ + lcol + kbase;
    const unsigned short* gBh = BThi + (size_t)(n0 + wave * 32 + lrow) * D_ + lcol + kbase;
    const unsigned short* gBl = BTlo + (size_t)(n0 + wave * 32 + lrow) * D_ + lcol + kbase;
    const int ldst = wave * 1024 + lane * 8;

    floatx4 acc[4][4];
#pragma unroll
    for (int i = 0; i < 4; i++)
#pragma unroll
        for (int j = 0; j < 4; j++)
#pragma unroll
            for (int r = 0; r < 4; r++) acc[i][j][r] = 0.f;

    for (int k0 = 0; k0 < 512; k0 += 32) {
        __syncthreads();
        dma16(gAh + k0, &sAh[ldst]);
        dma16(gAh + (size_t)16 * D_ + k0, &sAh[ldst + 512]);
        dma16(gAl + k0, &sAl[ldst]);
        dma16(gAl + (size_t)16 * D_ + k0, &sAl[ldst + 512]);
        dma16(gBh + k0, &sBh[ldst]);
        dma16(gBh + (size_t)16 * D_ + k0, &sBh[ldst + 512]);
        dma16(gBl + k0, &sBl[ldst]);
        dma16(gBl + (size_t)16 * D_ + k0, &sBl[ldst + 512]);
        __syncthreads();

        short8 bhf[4], blf[4];
#pragma unroll
        for (int nb = 0; nb < 4; nb++) {
            const int r = wn + nb * 16 + lm;
            bhf[nb] = *(const short8*)&sBh[r * 32 + quad * 8];
            blf[nb] = *(const short8*)&sBl[r * 32 + quad * 8];
        }
#pragma unroll
        for (int mb = 0; mb < 4; mb++) {
            const int r = wm + mb * 16 + lm;
            short8 ah = *(const short8*)&sAh[r * 32 + quad * 8];
            short8 al = *(const short8*)&sAl[r * 32 + quad * 8];
#pragma unroll
            for (int nb = 0; nb < 4; nb++) {
                acc[mb][nb] = __builtin_amdgcn_mfma_f32_16x16x32_bf16(ah, bhf[nb], acc[mb][nb], 0, 0, 0);
                acc[mb][nb] = __builtin_amdgcn_mfma_f32_16x16x32_bf16(al, bhf[nb], acc[mb][nb], 0, 0, 0);
                acc[mb][nb] = __builtin_amdgcn_mfma_f32_16x16x32_bf16(ah, blf[nb], acc[mb][nb], 0, 0, 0);
            }
        }
    }

    if (blockIdx.z == 0) {
#pragma unroll
        for (int nb = 0; nb < 4; nb++) {
            const int c = n0 + wn + nb * 16 + lm;
            const float bv = bias[c];
#pragma unroll
            for (int mb = 0; mb < 4; mb++) {
                const int rowb = m0 + wm + mb * 16 + quad * 4;
#pragma unroll
                for (int r = 0; r < 4; r++)
                    C[(size_t)(rowb + r) * D_ + c] = acc[mb][nb][r] + bv;
            }
        }
    } else {
#pragma unroll
        for (int nb = 0; nb < 4; nb++) {
            const int c = n0 + wn + nb * 16 + lm;
#pragma unroll
            for (int mb = 0; mb < 4; mb++) {
                const int rowb = m0 + wm + mb * 16 + quad * 4;
#pragma unroll
                for (int r = 0; r < 4; r++)
                    P[(size_t)(rowb + r) * D_ + c] = acc[mb][nb][r];
            }
        }
    }
}

// ---------------------------------------------------------------------------
// add_partial: C += P (float4, coalesced). 48 MB traffic ~ 10 us.
// ---------------------------------------------------------------------------
__global__ __launch_bounds__(256) void add_partial(
    float* __restrict__ C, const float* __restrict__ P)
{
    const size_t i = ((size_t)blockIdx.x * 256 + threadIdx.x) * 4;
    float4 c = *(const float4*)(C + i);
    float4 p = *(const float4*)(P + i);
    c.x += p.x; c.y += p.y; c.z += p.z; c.w += p.w;
    *(float4*)(C + i) = c;
}

// ---------------------------------------------------------------------------
// MFMA flash attention (unchanged from R6): DMA-staged XOR-swizzled K/V,
// 64-row Q tiles, 4 waves, 3 blocks/CU.
// ---------------------------------------------------------------------------
#define PSP 72   // P row stride (64 data + 8 pad)

__global__ __launch_bounds__(256, 3) void flash_attn_mfma(
    unsigned short* QAhi, unsigned short* QAlo,   // Q in, attn out (aliased)
    const unsigned short* __restrict__ Khi, const unsigned short* __restrict__ Klo,
    const unsigned short* __restrict__ vThi, const unsigned short* __restrict__ vTlo)
{
    __shared__ unsigned short KhS[64 * 64], KlS[64 * 64];   // swizzled, 8 KB ea
    __shared__ unsigned short VhS[64 * 64], VlS[64 * 64];   // V^T tile [d][s]
    __shared__ unsigned short PhS[64 * PSP], PlS[64 * PSP]; // 50 KB total

    const int t    = threadIdx.x;
    const int pj   = blockIdx.x;            // 0..15
    const int bh   = blockIdx.y;
    const int b    = bh >> 4, h = bh & 15;
    const int lane = t & 63, w = t >> 6;    // 4 waves
    const int lm   = lane & 15, quad = lane >> 4;

    const int r0  = t >> 3;                       // 0..31
    const int seg = (t & 7) ^ (r0 & 7);           // involution
    const unsigned short* gKh = Khi + (size_t)(b * S_ + r0) * D_ + h * HD + 8 * seg;
    const unsigned short* gKl = Klo + (size_t)(b * S_ + r0) * D_ + h * HD + 8 * seg;
    const unsigned short* gVh = vThi + ((size_t)((b * 16 + h) * 64 + r0)) * S_ + 8 * seg;
    const unsigned short* gVl = vTlo + ((size_t)((b * 16 + h) * 64 + r0)) * S_ + 8 * seg;
    const int ld0 = t * 8;                        // u16 dest chunk 0
    const int swzr = (lm & 7) << 3;               // read-side XOR (u16 units)

    for (int phse = 0; phse < 2; phse++) {
        const int qt = phse ? (31 - pj) : pj;
        const int q0 = qt * 64;
        const int ntiles = qt + 1;

        // Q fragments (A-layout rows q0+16w+lm), pre-scaled by 1/8
        short8 qh[2], ql[2];
        {
            const size_t qoff = (size_t)(b * S_ + q0 + 16 * w + lm) * D_ + h * HD + quad * 8;
            qh[0] = *(const short8*)&QAhi[qoff];
            qh[1] = *(const short8*)&QAhi[qoff + 32];
            ql[0] = *(const short8*)&QAlo[qoff];
            ql[1] = *(const short8*)&QAlo[qoff + 32];
        }

        float lsum[4] = {0.f, 0.f, 0.f, 0.f};
        floatx4 o[4];
#pragma unroll
        for (int nb = 0; nb < 4; nb++)
#pragma unroll
            for (int r = 0; r < 4; r++) o[nb][r] = 0.f;

        for (int kt = 0; kt < ntiles; kt++) {
            __syncthreads();   // all waves done reading previous tile
            {
                const size_t ko = (size_t)(kt * 64) * D_;
                const int vo = kt * 64;
                dma16(gKh + ko,                    &KhS[ld0]);
                dma16(gKh + ko + (size_t)32 * D_,  &KhS[ld0 + 2048]);
                dma16(gKl + ko,                    &KlS[ld0]);
                dma16(gKl + ko + (size_t)32 * D_,  &KlS[ld0 + 2048]);
                dma16(gVh + vo,                    &VhS[ld0]);
                dma16(gVh + vo + (size_t)32 * S_,  &VhS[ld0 + 2048]);
                dma16(gVl + vo,                    &VlS[ld0]);
                dma16(gVl + vo + (size_t)32 * S_,  &VlS[ld0 + 2048]);
            }
            __syncthreads();   // DMA drained (vmcnt0 at barrier)

            // ---- S = Q K^T (3-MFMA split), swizzled K reads
            floatx4 sa[4];
#pragma unroll
            for (int nb = 0; nb < 4; nb++)
#pragma unroll
                for (int r = 0; r < 4; r++) sa[nb][r] = 0.f;
            __builtin_amdgcn_s_setprio(1);
#pragma unroll
            for (int s = 0; s < 2; s++) {
#pragma unroll
                for (int nb = 0; nb < 4; nb++) {
                    const int ka = (nb * 16 + lm) * 64 + ((s * 32 + quad * 8) ^ swzr);
                    short8 kh = *(const short8*)&KhS[ka];
                    short8 kl = *(const short8*)&KlS[ka];
                    sa[nb] = __builtin_amdgcn_mfma_f32_16x16x32_bf16(qh[s], kh, sa[nb], 0, 0, 0);
                    sa[nb] = __builtin_amdgcn_mfma_f32_16x16x32_bf16(ql[s], kh, sa[nb], 0, 0, 0);
                    sa[nb] = __builtin_amdgcn_mfma_f32_16x16x32_bf16(qh[s], kl, sa[nb], 0, 0, 0);
                }
            }
            __builtin_amdgcn_s_setprio(0);

            // ---- softmax-lite (no shift); mask only on the diag (=last) tile
            const bool diag = (kt == qt);
            const int kbase = kt * 64;
#pragma unroll
            for (int r = 0; r < 4; r++) {
                const int qabs = q0 + 16 * w + 4 * quad + r;
                const int rloc = 16 * w + 4 * quad + r;
#pragma unroll
                for (int nb = 0; nb < 4; nb++) {
                    float p = __expf(sa[nb][r]);
                    if (diag && (kbase + 16 * nb + lm > qabs)) p = 0.f;
                    lsum[r] += p;
                    unsigned short hh, ll;
                    split2(p, hh, ll);
                    PhS[rloc * PSP + 16 * nb + lm] = hh;
                    PlS[rloc * PSP + 16 * nb + lm] = ll;
                }
            }

            // ---- O += P V (same-wave P rows; swizzled V reads)
            __builtin_amdgcn_s_setprio(1);
#pragma unroll
            for (int ks = 0; ks < 2; ks++) {
                short8 pf = *(const short8*)&PhS[(16 * w + lm) * PSP + ks * 32 + quad * 8];
                short8 pg = *(const short8*)&PlS[(16 * w + lm) * PSP + ks * 32 + quad * 8];
#pragma unroll
                for (int nb = 0; nb < 4; nb++) {
                    const int va = (nb * 16 + lm) * 64 + ((ks * 32 + quad * 8) ^ swzr);
                    short8 vhf = *(const short8*)&VhS[va];
                    short8 vlf = *(const short8*)&VlS[va];
                    o[nb] = __builtin_amdgcn_mfma_f32_16x16x32_bf16(pf, vhf, o[nb], 0, 0, 0);
                    o[nb] = __builtin_amdgcn_mfma_f32_16x16x32_bf16(pg, vhf, o[nb], 0, 0, 0);
                    o[nb] = __builtin_amdgcn_mfma_f32_16x16x32_bf16(pf, vlf, o[nb], 0, 0, 0);
                }
            }
            __builtin_amdgcn_s_setprio(0);
        }

        // epilogue: reduce l, normalize, write attn PRE-SPLIT into Q buffers
#pragma unroll
        for (int r = 0; r < 4; r++) {
            float l = lsum[r];
            l += __shfl_xor(l, 1);
            l += __shfl_xor(l, 2);
            l += __shfl_xor(l, 4);
            l += __shfl_xor(l, 8);
            const float inv = 1.f / l;
            const size_t rowoff =
                (size_t)(b * S_ + q0 + 16 * w + 4 * quad + r) * D_ + h * HD + lm;
#pragma unroll
            for (int nb = 0; nb < 4; nb++) {
                unsigned short hh, ll;
                split2(o[nb][r] * inv, hh, ll);
                QAhi[rowoff + 16 * nb] = hh;
                QAlo[rowoff + 16 * nb] = ll;
            }
        }
    }
}

// ---------------------------------------------------------------------------
extern "C" void kernel_launch(void* const* d_in, const int* in_sizes, int n_in,
                              void* d_out, int out_size, void* d_ws, size_t ws_size,
                              hipStream_t stream)
{
    const float* hs     = (const float*)d_in[0];
    const float* attn_w = (const float*)d_in[1];
    const float* attn_b = (const float*)d_in[2];
    const float* proj_w = (const float*)d_in[3];
    const float* proj_b = (const float*)d_in[4];
    float* outp = (float*)d_out;

    const size_t QE = (size_t)M_ * D_;          // 4,194,304
    const size_t WQ = (size_t)D_ * N_QKV;       // 3,145,728
    unsigned short* Qhi   = (unsigned short*)d_ws;       // also attn hi
    unsigned short* Qlo   = Qhi + QE;                    // also attn lo
    unsigned short* Khi   = Qlo + QE;
    unsigned short* Klo   = Khi + QE;
    unsigned short* vThi  = Klo + QE;
    unsigned short* vTlo  = vThi + QE;
    unsigned short* WqThi = vTlo + QE;
    unsigned short* WqTlo = WqThi + WQ;
    unsigned short* WpThi = WqTlo + WQ;
    unsigned short* WpTlo = WpThi + (size_t)D_ * D_;
    unsigned short* Ahi   = WpTlo + (size_t)D_ * D_;     // hs pre-split
    unsigned short* Alo   = Ahi + QE;                    // total = 80 MB

    // split-K partial: reuse Khi+Klo (dead after flash; exactly M_*D_ floats)
    float* Pbuf = (float*)Khi;

    dim3 blk(256);
    prep_A<<<dim3(M_ * D_ / 2048), blk, 0, stream>>>(hs, Ahi, Alo);
    prep_wT<<<dim3(N_QKV / 64, D_ / 64), blk, 0, stream>>>(attn_w, N_QKV, WqThi, WqTlo);
    prep_wT<<<dim3(D_ / 64, D_ / 64), blk, 0, stream>>>(proj_w, D_, WpThi, WpTlo);
    gemm_qkv<<<dim3(N_QKV / 128, M_ / 128), blk, 0, stream>>>(
        Ahi, Alo, WqThi, WqTlo, attn_b, Qhi, Qlo, Khi, Klo, vThi, vTlo);
    flash_attn_mfma<<<dim3(16, B_ * H_), dim3(256), 0, stream>>>(
        Qhi, Qlo, Khi, Klo, vThi, vTlo);
    gemm_out<<<dim3(D_ / 128, M_ / 128, 2), blk, 0, stream>>>(
        Qhi, Qlo, WpThi, WpTlo, proj_b, outp, Pbuf);
    add_partial<<<dim3(M_ * D_ / 1024), blk, 0, stream>>>(outp, Pbuf);
}

// Round 9
// 307.529 us; speedup vs baseline: 1.0302x; 1.0302x over previous
//
#include <hip/hip_runtime.h>
#include <hip/hip_bf16.h>
#include <math.h>

#define B_ 2
#define S_ 2048
#define D_ 1024
#define H_ 16
#define HD 64
#define M_ (B_ * S_)     // 4096
#define N_QKV (3 * D_)   // 3072

typedef short short8 __attribute__((ext_vector_type(8)));
typedef float floatx4 __attribute__((ext_vector_type(4)));

// HW RNE f32->bf16 (compiler emits v_cvt_pk_bf16_f32)
static __device__ __forceinline__ unsigned short f2bf(float x) {
    __hip_bfloat16 h = __float2bfloat16(x);
    unsigned short u;
    __builtin_memcpy(&u, &h, sizeof(u));
    return u;
}
static __device__ __forceinline__ float bf2f(unsigned short b) {
    union { unsigned u; float f; } v; v.u = ((unsigned)b) << 16;
    return v.f;
}
// RNE split: x = hi + lo + eps, |eps| ~ 2^-17 |x|
static __device__ __forceinline__ void split2(float x, unsigned short& h, unsigned short& l) {
    h = f2bf(x);
    l = f2bf(x - bf2f(h));
}

// async global->LDS DMA, 16 B per lane (dest = wave-uniform base + lane*16)
static __device__ __forceinline__ void dma16(const void* g, void* l) {
    __builtin_amdgcn_global_load_lds(
        (const __attribute__((address_space(1))) unsigned int*)g,
        (__attribute__((address_space(3))) unsigned int*)l,
        16, 0, 0);
}

// ---------------------------------------------------------------------------
// prep_A: hs fp32 [4096][1024] -> Ahi/Alo bf16.
// ---------------------------------------------------------------------------
__global__ __launch_bounds__(256) void prep_A(
    const float* __restrict__ X,
    unsigned short* __restrict__ Ahi, unsigned short* __restrict__ Alo)
{
    const size_t i = ((size_t)blockIdx.x * 256 + threadIdx.x) * 8;
    float4 a = *(const float4*)(X + i);
    float4 b = *(const float4*)(X + i + 4);
    float xs[8] = {a.x, a.y, a.z, a.w, b.x, b.y, b.z, b.w};
    short8 h, l;
#pragma unroll
    for (int e = 0; e < 8; e++) {
        unsigned short hh, ll;
        split2(xs[e], hh, ll);
        h[e] = (short)hh; l[e] = (short)ll;
    }
    *(short8*)&Ahi[i] = h;
    *(short8*)&Alo[i] = l;
}

// ---------------------------------------------------------------------------
// prep_wT: W[K=1024][N] fp32 -> WT hi/lo bf16 [N][1024]. (verified)
// ---------------------------------------------------------------------------
__global__ __launch_bounds__(256) void prep_wT(
    const float* __restrict__ W, int N,
    unsigned short* __restrict__ Thi, unsigned short* __restrict__ Tlo)
{
    __shared__ float Ws[64][68];
    const int t  = threadIdx.x;
    const int n0 = blockIdx.x * 64, k0 = blockIdx.y * 64;
    {
        const int kl = t >> 4, nl = (t & 15) * 4;
        const float* src = W + (size_t)(k0 + kl) * N + n0 + nl;
#pragma unroll
        for (int g = 0; g < 4; g++)
            *(float4*)&Ws[kl + g * 16][nl] = *(const float4*)(src + (size_t)g * 16 * N);
    }
    __syncthreads();
    {
        const int nl = t >> 2, ks = (t & 3) * 16;
        short8 h0, h1, l0, l1;
#pragma unroll
        for (int j = 0; j < 8; j++) {
            unsigned short hh, ll;
            split2(Ws[ks + j][nl], hh, ll);
            h0[j] = (short)hh; l0[j] = (short)ll;
        }
#pragma unroll
        for (int j = 0; j < 8; j++) {
            unsigned short hh, ll;
            split2(Ws[ks + 8 + j][nl], hh, ll);
            h1[j] = (short)hh; l1[j] = (short)ll;
        }
        unsigned short* dh = Thi + (size_t)(n0 + nl) * D_ + k0 + ks;
        unsigned short* dl = Tlo + (size_t)(n0 + nl) * D_ + k0 + ks;
        *(short8*)dh = h0; *(short8*)(dh + 8) = h1;
        *(short8*)dl = l0; *(short8*)(dl + 8) = l1;
    }
}

// ---------------------------------------------------------------------------
// QKV GEMM (unchanged, measured ~107 us): m97 structure, 128x128 tile,
// single 32KB buffer, fully-DMA staging, zero K-loop VALU.
// ---------------------------------------------------------------------------
__global__ __launch_bounds__(256) void gemm_qkv(
    const unsigned short* __restrict__ Ahi, const unsigned short* __restrict__ Alo,
    const unsigned short* __restrict__ BThi, const unsigned short* __restrict__ BTlo,
    const float* __restrict__ bias,
    unsigned short* __restrict__ Qhi, unsigned short* __restrict__ Qlo,
    unsigned short* __restrict__ Khi, unsigned short* __restrict__ Klo,
    unsigned short* __restrict__ vThi, unsigned short* __restrict__ vTlo)
{
    __shared__ unsigned short sAh[128 * 32], sAl[128 * 32];
    __shared__ unsigned short sBh[128 * 32], sBl[128 * 32];   // 32 KB

    const int t    = threadIdx.x;
    const int m0   = blockIdx.y * 128, n0 = blockIdx.x * 128;
    const int lane = t & 63, wave = t >> 6;
    const int lm   = lane & 15, quad = lane >> 4;
    const int wm   = (wave >> 1) * 64, wn = (wave & 1) * 64;

    const int lrow = lane >> 2, lcol = (lane & 3) * 8;
    const unsigned short* gAh = Ahi + (size_t)(m0 + wave * 32 + lrow) * D_ + lcol;
    const unsigned short* gAl = Alo + (size_t)(m0 + wave * 32 + lrow) * D_ + lcol;
    const unsigned short* gBh = BThi + (size_t)(n0 + wave * 32 + lrow) * D_ + lcol;
    const unsigned short* gBl = BTlo + (size_t)(n0 + wave * 32 + lrow) * D_ + lcol;
    const int ldst = wave * 1024 + lane * 8;   // u16 dest (= base + lane*16B)

    floatx4 acc[4][4];
#pragma unroll
    for (int i = 0; i < 4; i++)
#pragma unroll
        for (int j = 0; j < 4; j++)
#pragma unroll
            for (int r = 0; r < 4; r++) acc[i][j][r] = 0.f;

    for (int k0 = 0; k0 < D_; k0 += 32) {
        __syncthreads();   // readers of previous tile done
        dma16(gAh + k0, &sAh[ldst]);
        dma16(gAh + (size_t)16 * D_ + k0, &sAh[ldst + 512]);
        dma16(gAl + k0, &sAl[ldst]);
        dma16(gAl + (size_t)16 * D_ + k0, &sAl[ldst + 512]);
        dma16(gBh + k0, &sBh[ldst]);
        dma16(gBh + (size_t)16 * D_ + k0, &sBh[ldst + 512]);
        dma16(gBl + k0, &sBl[ldst]);
        dma16(gBl + (size_t)16 * D_ + k0, &sBl[ldst + 512]);
        __syncthreads();   // staged (compiler drains vmcnt(0) here)

        short8 bhf[4], blf[4];
#pragma unroll
        for (int nb = 0; nb < 4; nb++) {
            const int r = wn + nb * 16 + lm;
            bhf[nb] = *(const short8*)&sBh[r * 32 + quad * 8];
            blf[nb] = *(const short8*)&sBl[r * 32 + quad * 8];
        }
#pragma unroll
        for (int mb = 0; mb < 4; mb++) {
            const int r = wm + mb * 16 + lm;
            short8 ah = *(const short8*)&sAh[r * 32 + quad * 8];
            short8 al = *(const short8*)&sAl[r * 32 + quad * 8];
#pragma unroll
            for (int nb = 0; nb < 4; nb++) {
                acc[mb][nb] = __builtin_amdgcn_mfma_f32_16x16x32_bf16(ah, bhf[nb], acc[mb][nb], 0, 0, 0);
                acc[mb][nb] = __builtin_amdgcn_mfma_f32_16x16x32_bf16(al, bhf[nb], acc[mb][nb], 0, 0, 0);
                acc[mb][nb] = __builtin_amdgcn_mfma_f32_16x16x32_bf16(ah, blf[nb], acc[mb][nb], 0, 0, 0);
            }
        }
    }

    const int nmode = n0 >> 10;
    if (nmode == 0) {
#pragma unroll
        for (int nb = 0; nb < 4; nb++) {
            const int c = n0 + wn + nb * 16 + lm;
            const float bv = bias[c];
#pragma unroll
            for (int mb = 0; mb < 4; mb++) {
                const int rowb = m0 + wm + mb * 16 + quad * 4;
#pragma unroll
                for (int r = 0; r < 4; r++) {
                    unsigned short hh, ll;
                    split2((acc[mb][nb][r] + bv) * 0.125f, hh, ll);
                    Qhi[(size_t)(rowb + r) * D_ + c] = hh;
                    Qlo[(size_t)(rowb + r) * D_ + c] = ll;
                }
            }
        }
    } else if (nmode == 1) {
#pragma unroll
        for (int nb = 0; nb < 4; nb++) {
            const int c = n0 + wn + nb * 16 + lm;
            const float bv = bias[c];
            const int cq = c - 1024;
#pragma unroll
            for (int mb = 0; mb < 4; mb++) {
                const int rowb = m0 + wm + mb * 16 + quad * 4;
#pragma unroll
                for (int r = 0; r < 4; r++) {
                    unsigned short hh, ll;
                    split2(acc[mb][nb][r] + bv, hh, ll);
                    Khi[(size_t)(rowb + r) * D_ + cq] = hh;
                    Klo[(size_t)(rowb + r) * D_ + cq] = ll;
                }
            }
        }
    } else {
#pragma unroll
        for (int nb = 0; nb < 4; nb++) {
            const int c = n0 + wn + nb * 16 + lm;
            const float bv = bias[c];
            const int cq = c - 2048;
            const int hh_ = cq >> 6, dd = cq & 63;
#pragma unroll
            for (int mb = 0; mb < 4; mb++) {
                const int rowb = m0 + wm + mb * 16 + quad * 4;
                const int bb = rowb >> 11, ss = rowb & 2047;
                unsigned short hv[4], lv[4];
#pragma unroll
                for (int r = 0; r < 4; r++)
                    split2(acc[mb][nb][r] + bv, hv[r], lv[r]);
                const size_t idx = ((size_t)((bb * 16 + hh_) * 64 + dd)) * S_ + ss;
                *(uint2*)&vThi[idx] = make_uint2((unsigned)hv[0] | ((unsigned)hv[1] << 16),
                                                 (unsigned)hv[2] | ((unsigned)hv[3] << 16));
                *(uint2*)&vTlo[idx] = make_uint2((unsigned)lv[0] | ((unsigned)lv[1] << 16),
                                                 (unsigned)lv[2] | ((unsigned)lv[3] << 16));
            }
        }
    }
}

// ---------------------------------------------------------------------------
// Proj GEMM (R6-verified best): 64x64 tiles, 1024 blocks = 4/CU, 16 KB LDS,
// fully-DMA 2-barrier structure, XCD-chunk swizzle. Plain stores.
// ---------------------------------------------------------------------------
__global__ __launch_bounds__(256) void gemm_out(
    const unsigned short* __restrict__ Ahi, const unsigned short* __restrict__ Alo,
    const unsigned short* __restrict__ BThi, const unsigned short* __restrict__ BTlo,
    const float* __restrict__ bias, float* __restrict__ C)
{
    __shared__ unsigned short sAh[64 * 32], sAl[64 * 32];
    __shared__ unsigned short sBh[64 * 32], sBl[64 * 32];   // 16 KB

    const int t   = threadIdx.x;
    const int lid = blockIdx.x;                        // 0..1023
    const int swz = (lid & 7) * 128 + (lid >> 3);      // XCD-chunk, bijective
    const int bx  = swz & 15, by = swz >> 4;
    const int m0  = by * 64, n0 = bx * 64;
    const int lane = t & 63, wave = t >> 6;
    const int lm   = lane & 15, quad = lane >> 4;

    const int lrow = lane >> 2, lcol = (lane & 3) * 8;
    const unsigned short* gAh = Ahi + (size_t)(m0 + wave * 16 + lrow) * D_ + lcol;
    const unsigned short* gAl = Alo + (size_t)(m0 + wave * 16 + lrow) * D_ + lcol;
    const unsigned short* gBh = BThi + (size_t)(n0 + wave * 16 + lrow) * D_ + lcol;
    const unsigned short* gBl = BTlo + (size_t)(n0 + wave * 16 + lrow) * D_ + lcol;
    unsigned short* lAh = sAh + wave * 512 + lane * 8;
    unsigned short* lAl = sAl + wave * 512 + lane * 8;
    unsigned short* lBh = sBh + wave * 512 + lane * 8;
    unsigned short* lBl = sBl + wave * 512 + lane * 8;

    floatx4 acc[4];
#pragma unroll
    for (int j = 0; j < 4; j++)
#pragma unroll
        for (int r = 0; r < 4; r++) acc[j][r] = 0.f;

    for (int k0 = 0; k0 < D_; k0 += 32) {
        __syncthreads();
        dma16(gAh + k0, lAh);
        dma16(gAl + k0, lAl);
        dma16(gBh + k0, lBh);
        dma16(gBl + k0, lBl);
        __syncthreads();

        short8 ah = *(const short8*)&sAh[(wave * 16 + lm) * 32 + quad * 8];
        short8 al = *(const short8*)&sAl[(wave * 16 + lm) * 32 + quad * 8];
#pragma unroll
        for (int nb = 0; nb < 4; nb++) {
            short8 bh = *(const short8*)&sBh[(nb * 16 + lm) * 32 + quad * 8];
            short8 bl = *(const short8*)&sBl[(nb * 16 + lm) * 32 + quad * 8];
            acc[nb] = __builtin_amdgcn_mfma_f32_16x16x32_bf16(ah, bh, acc[nb], 0, 0, 0);
            acc[nb] = __builtin_amdgcn_mfma_f32_16x16x32_bf16(al, bh, acc[nb], 0, 0, 0);
            acc[nb] = __builtin_amdgcn_mfma_f32_16x16x32_bf16(ah, bl, acc[nb], 0, 0, 0);
        }
    }

#pragma unroll
    for (int nb = 0; nb < 4; nb++) {
        const int col = n0 + nb * 16 + lm;
        const float bv = bias[col];
#pragma unroll
        for (int r = 0; r < 4; r++) {
            const int row = m0 + wave * 16 + quad * 4 + r;
            C[(size_t)row * D_ + col] = acc[nb][r] + bv;
        }
    }
}

// ---------------------------------------------------------------------------
// MFMA flash attention v6 (wdiag FIX: w>>2, not w>>3): 128-row Q super-tile,
// 8 waves / 512 threads, DMA-staged XOR-swizzled K/V (1 dma16/thread/array
// per k-tile). Each staged 64-row K/V tile serves 128 Q rows. Grid (16,32)
// = 512 blocks = 2/CU (68 KB LDS); cross-block balance pairing (b=0: qt=pj,
// b=1: qt=15-pj). Per-wave causal skip past diagonal tile (R2-verified).
// ---------------------------------------------------------------------------
#define PSP 72   // P row stride (64 data + 8 pad)

__global__ __launch_bounds__(512, 4) void flash_attn_mfma(
    unsigned short* QAhi, unsigned short* QAlo,   // Q in, attn out (aliased)
    const unsigned short* __restrict__ Khi, const unsigned short* __restrict__ Klo,
    const unsigned short* __restrict__ vThi, const unsigned short* __restrict__ vTlo)
{
    __shared__ unsigned short KhS[64 * 64], KlS[64 * 64];   // swizzled, 8 KB ea
    __shared__ unsigned short VhS[64 * 64], VlS[64 * 64];   // V^T tile [d][s]
    __shared__ unsigned short PhS[128 * PSP], PlS[128 * PSP]; // 68 KB total

    const int t    = threadIdx.x;           // 0..511
    const int pj   = blockIdx.x;            // 0..15
    const int bh   = blockIdx.y;            // 0..31
    const int b    = bh >> 4, h = bh & 15;
    const int lane = t & 63, w = t >> 6;    // 8 waves
    const int lm   = lane & 15, quad = lane >> 4;

    const int qt = (bh < 16) ? pj : (15 - pj);  // balance pairing
    const int q0 = qt * 128;
    const int ntiles = 2 * qt + 2;
    const int wdiag = (q0 >> 6) + (w >> 2);     // waves 0-3: 2qt; 4-7: 2qt+1

    // staging geometry: thread t covers row r0 = t>>3 (0..63), col-seg
    // inverse-swizzled so linear DMA lands swizzled (rule #21).
    const int r0  = t >> 3;                       // 0..63
    const int seg = (t & 7) ^ (r0 & 7);           // involution
    const unsigned short* gKh = Khi + (size_t)(b * S_ + r0) * D_ + h * HD + 8 * seg;
    const unsigned short* gKl = Klo + (size_t)(b * S_ + r0) * D_ + h * HD + 8 * seg;
    const unsigned short* gVh = vThi + ((size_t)((b * 16 + h) * 64 + r0)) * S_ + 8 * seg;
    const unsigned short* gVl = vTlo + ((size_t)((b * 16 + h) * 64 + r0)) * S_ + 8 * seg;
    const int ld0 = t * 8;                        // u16 dest (= base + t*16B)
    const int swzr = (lm & 7) << 3;               // read-side XOR (u16 units)

    // Q fragments (A-layout rows q0+16w+lm), pre-scaled by 1/8
    short8 qh[2], ql[2];
    {
        const size_t qoff = (size_t)(b * S_ + q0 + 16 * w + lm) * D_ + h * HD + quad * 8;
        qh[0] = *(const short8*)&QAhi[qoff];
        qh[1] = *(const short8*)&QAhi[qoff + 32];
        ql[0] = *(const short8*)&QAlo[qoff];
        ql[1] = *(const short8*)&QAlo[qoff + 32];
    }

    float lsum[4] = {0.f, 0.f, 0.f, 0.f};
    floatx4 o[4];
#pragma unroll
    for (int nb = 0; nb < 4; nb++)
#pragma unroll
        for (int r = 0; r < 4; r++) o[nb][r] = 0.f;

    for (int kt = 0; kt < ntiles; kt++) {
        __syncthreads();   // all waves done reading previous tile
        {
            const size_t ko = (size_t)(kt * 64) * D_;
            const int vo = kt * 64;
            dma16(gKh + ko, &KhS[ld0]);
            dma16(gKl + ko, &KlS[ld0]);
            dma16(gVh + vo, &VhS[ld0]);
            dma16(gVl + vo, &VlS[ld0]);
        }
        __syncthreads();   // DMA drained (vmcnt0 at barrier)

        if (kt <= wdiag) {   // wave-uniform causal skip
            // ---- S = Q K^T (3-MFMA split), swizzled K reads
            floatx4 sa[4];
#pragma unroll
            for (int nb = 0; nb < 4; nb++)
#pragma unroll
                for (int r = 0; r < 4; r++) sa[nb][r] = 0.f;
            __builtin_amdgcn_s_setprio(1);
#pragma unroll
            for (int s = 0; s < 2; s++) {
#pragma unroll
                for (int nb = 0; nb < 4; nb++) {
                    const int ka = (nb * 16 + lm) * 64 + ((s * 32 + quad * 8) ^ swzr);
                    short8 kh = *(const short8*)&KhS[ka];
                    short8 kl = *(const short8*)&KlS[ka];
                    sa[nb] = __builtin_amdgcn_mfma_f32_16x16x32_bf16(qh[s], kh, sa[nb], 0, 0, 0);
                    sa[nb] = __builtin_amdgcn_mfma_f32_16x16x32_bf16(ql[s], kh, sa[nb], 0, 0, 0);
                    sa[nb] = __builtin_amdgcn_mfma_f32_16x16x32_bf16(qh[s], kl, sa[nb], 0, 0, 0);
                }
            }
            __builtin_amdgcn_s_setprio(0);

            // ---- softmax-lite (no shift); mask only on the diag tile
            const bool diag = (kt == wdiag);
            const int kbase = kt * 64;
#pragma unroll
            for (int r = 0; r < 4; r++) {
                const int qabs = q0 + 16 * w + 4 * quad + r;
                const int rloc = 16 * w + 4 * quad + r;
#pragma unroll
                for (int nb = 0; nb < 4; nb++) {
                    float p = __expf(sa[nb][r]);
                    if (diag && (kbase + 16 * nb + lm > qabs)) p = 0.f;
                    lsum[r] += p;
                    unsigned short hh, ll;
                    split2(p, hh, ll);
                    PhS[rloc * PSP + 16 * nb + lm] = hh;
                    PlS[rloc * PSP + 16 * nb + lm] = ll;
                }
            }

            // ---- O += P V (same-wave P rows; swizzled V reads)
            __builtin_amdgcn_s_setprio(1);
#pragma unroll
            for (int ks = 0; ks < 2; ks++) {
                short8 pf = *(const short8*)&PhS[(16 * w + lm) * PSP + ks * 32 + quad * 8];
                short8 pg = *(const short8*)&PlS[(16 * w + lm) * PSP + ks * 32 + quad * 8];
#pragma unroll
                for (int nb = 0; nb < 4; nb++) {
                    const int va = (nb * 16 + lm) * 64 + ((ks * 32 + quad * 8) ^ swzr);
                    short8 vhf = *(const short8*)&VhS[va];
                    short8 vlf = *(const short8*)&VlS[va];
                    o[nb] = __builtin_amdgcn_mfma_f32_16x16x32_bf16(pf, vhf, o[nb], 0, 0, 0);
                    o[nb] = __builtin_amdgcn_mfma_f32_16x16x32_bf16(pg, vhf, o[nb], 0, 0, 0);
                    o[nb] = __builtin_amdgcn_mfma_f32_16x16x32_bf16(pf, vlf, o[nb], 0, 0, 0);
                }
            }
            __builtin_amdgcn_s_setprio(0);
        }
    }

    // epilogue: reduce l, normalize, write attn PRE-SPLIT into Q buffers
#pragma unroll
    for (int r = 0; r < 4; r++) {
        float l = lsum[r];
        l += __shfl_xor(l, 1);
        l += __shfl_xor(l, 2);
        l += __shfl_xor(l, 4);
        l += __shfl_xor(l, 8);
        const float inv = 1.f / l;
        const size_t rowoff =
            (size_t)(b * S_ + q0 + 16 * w + 4 * quad + r) * D_ + h * HD + lm;
#pragma unroll
        for (int nb = 0; nb < 4; nb++) {
            unsigned short hh, ll;
            split2(o[nb][r] * inv, hh, ll);
            QAhi[rowoff + 16 * nb] = hh;
            QAlo[rowoff + 16 * nb] = ll;
        }
    }
}

// ---------------------------------------------------------------------------
extern "C" void kernel_launch(void* const* d_in, const int* in_sizes, int n_in,
                              void* d_out, int out_size, void* d_ws, size_t ws_size,
                              hipStream_t stream)
{
    const float* hs     = (const float*)d_in[0];
    const float* attn_w = (const float*)d_in[1];
    const float* attn_b = (const float*)d_in[2];
    const float* proj_w = (const float*)d_in[3];
    const float* proj_b = (const float*)d_in[4];
    float* outp = (float*)d_out;

    const size_t QE = (size_t)M_ * D_;          // 4,194,304
    const size_t WQ = (size_t)D_ * N_QKV;       // 3,145,728
    unsigned short* Qhi   = (unsigned short*)d_ws;       // also attn hi
    unsigned short* Qlo   = Qhi + QE;                    // also attn lo
    unsigned short* Khi   = Qlo + QE;
    unsigned short* Klo   = Khi + QE;
    unsigned short* vThi  = Klo + QE;
    unsigned short* vTlo  = vThi + QE;
    unsigned short* WqThi = vTlo + QE;
    unsigned short* WqTlo = WqThi + WQ;
    unsigned short* WpThi = WqTlo + WQ;
    unsigned short* WpTlo = WpThi + (size_t)D_ * D_;
    unsigned short* Ahi   = WpTlo + (size_t)D_ * D_;     // hs pre-split
    unsigned short* Alo   = Ahi + QE;                    // total = 80 MB

    dim3 blk(256);
    prep_A<<<dim3(M_ * D_ / 2048), blk, 0, stream>>>(hs, Ahi, Alo);
    prep_wT<<<dim3(N_QKV / 64, D_ / 64), blk, 0, stream>>>(attn_w, N_QKV, WqThi, WqTlo);
    prep_wT<<<dim3(D_ / 64, D_ / 64), blk, 0, stream>>>(proj_w, D_, WpThi, WpTlo);
    gemm_qkv<<<dim3(N_QKV / 128, M_ / 128), blk, 0, stream>>>(
        Ahi, Alo, WqThi, WqTlo, attn_b, Qhi, Qlo, Khi, Klo, vThi, vTlo);
    flash_attn_mfma<<<dim3(16, B_ * H_), dim3(512), 0, stream>>>(
        Qhi, Qlo, Khi, Klo, vThi, vTlo);
    gemm_out<<<dim3(1024), blk, 0, stream>>>(
        Qhi, Qlo, WpThi, WpTlo, proj_b, outp);
}

// Round 10
// 301.859 us; speedup vs baseline: 1.0496x; 1.0188x over previous
//
#include <hip/hip_runtime.h>
#include <hip/hip_bf16.h>
#include <math.h>

#define B_ 2
#define S_ 2048
#define D_ 1024
#define H_ 16
#define HD 64
#define M_ (B_ * S_)     // 4096
#define N_QKV (3 * D_)   // 3072

typedef short short8 __attribute__((ext_vector_type(8)));
typedef float floatx4 __attribute__((ext_vector_type(4)));

// HW RNE f32->bf16 (compiler emits v_cvt_pk_bf16_f32)
static __device__ __forceinline__ unsigned short f2bf(float x) {
    __hip_bfloat16 h = __float2bfloat16(x);
    unsigned short u;
    __builtin_memcpy(&u, &h, sizeof(u));
    return u;
}
static __device__ __forceinline__ float bf2f(unsigned short b) {
    union { unsigned u; float f; } v; v.u = ((unsigned)b) << 16;
    return v.f;
}
// RNE split: x = hi + lo + eps, |eps| ~ 2^-17 |x|
static __device__ __forceinline__ void split2(float x, unsigned short& h, unsigned short& l) {
    h = f2bf(x);
    l = f2bf(x - bf2f(h));
}

// async global->LDS DMA, 16 B per lane (dest = wave-uniform base + lane*16)
static __device__ __forceinline__ void dma16(const void* g, void* l) {
    __builtin_amdgcn_global_load_lds(
        (const __attribute__((address_space(1))) unsigned int*)g,
        (__attribute__((address_space(3))) unsigned int*)l,
        16, 0, 0);
}

// ---------------------------------------------------------------------------
// prep_all: ONE dispatch for all preprocessing (saves 2 launch gaps, overlaps
// the small weight transposes with the big elementwise split).
//   blocks [0, 2048):        hs fp32 -> Ahi/Alo bf16 (elementwise)
//   blocks [2048, 2816):     attn_w [1024][3072] -> WqT hi/lo [3072][1024]
//   blocks [2816, 3072):     proj_w [1024][1024] -> WpT hi/lo [1024][1024]
// ---------------------------------------------------------------------------
__global__ __launch_bounds__(256) void prep_all(
    const float* __restrict__ hs,
    const float* __restrict__ attn_w,
    const float* __restrict__ proj_w,
    unsigned short* __restrict__ Ahi, unsigned short* __restrict__ Alo,
    unsigned short* __restrict__ WqThi, unsigned short* __restrict__ WqTlo,
    unsigned short* __restrict__ WpThi, unsigned short* __restrict__ WpTlo)
{
    __shared__ float Ws[64][68];
    const int bid = blockIdx.x;
    const int t   = threadIdx.x;

    if (bid < 2048) {   // ---- elementwise A split
        const size_t i = ((size_t)bid * 256 + t) * 8;
        float4 a = *(const float4*)(hs + i);
        float4 b = *(const float4*)(hs + i + 4);
        float xs[8] = {a.x, a.y, a.z, a.w, b.x, b.y, b.z, b.w};
        short8 h, l;
#pragma unroll
        for (int e = 0; e < 8; e++) {
            unsigned short hh, ll;
            split2(xs[e], hh, ll);
            h[e] = (short)hh; l[e] = (short)ll;
        }
        *(short8*)&Ahi[i] = h;
        *(short8*)&Alo[i] = l;
        return;
    }

    // ---- weight transpose+split sections
    const float* W; unsigned short *Thi, *Tlo; int N, n0, k0;
    if (bid < 2816) {
        const int s = bid - 2048;            // 0..767 = 48 x 16
        W = attn_w; Thi = WqThi; Tlo = WqTlo; N = N_QKV;
        n0 = (s % 48) * 64; k0 = (s / 48) * 64;
    } else {
        const int s = bid - 2816;            // 0..255 = 16 x 16
        W = proj_w; Thi = WpThi; Tlo = WpTlo; N = D_;
        n0 = (s % 16) * 64; k0 = (s / 16) * 64;
    }
    {
        const int kl = t >> 4, nl = (t & 15) * 4;
        const float* src = W + (size_t)(k0 + kl) * N + n0 + nl;
#pragma unroll
        for (int g = 0; g < 4; g++)
            *(float4*)&Ws[kl + g * 16][nl] = *(const float4*)(src + (size_t)g * 16 * N);
    }
    __syncthreads();
    {
        const int nl = t >> 2, ks = (t & 3) * 16;
        short8 h0, h1, l0, l1;
#pragma unroll
        for (int j = 0; j < 8; j++) {
            unsigned short hh, ll;
            split2(Ws[ks + j][nl], hh, ll);
            h0[j] = (short)hh; l0[j] = (short)ll;
        }
#pragma unroll
        for (int j = 0; j < 8; j++) {
            unsigned short hh, ll;
            split2(Ws[ks + 8 + j][nl], hh, ll);
            h1[j] = (short)hh; l1[j] = (short)ll;
        }
        unsigned short* dh = Thi + (size_t)(n0 + nl) * D_ + k0 + ks;
        unsigned short* dl = Tlo + (size_t)(n0 + nl) * D_ + k0 + ks;
        *(short8*)dh = h0; *(short8*)(dh + 8) = h1;
        *(short8*)dl = l0; *(short8*)(dl + 8) = l1;
    }
}

// ---------------------------------------------------------------------------
// QKV GEMM (unchanged, measured ~107 us): m97 structure, 128x128 tile,
// single 32KB buffer, fully-DMA staging, zero K-loop VALU.
// ---------------------------------------------------------------------------
__global__ __launch_bounds__(256) void gemm_qkv(
    const unsigned short* __restrict__ Ahi, const unsigned short* __restrict__ Alo,
    const unsigned short* __restrict__ BThi, const unsigned short* __restrict__ BTlo,
    const float* __restrict__ bias,
    unsigned short* __restrict__ Qhi, unsigned short* __restrict__ Qlo,
    unsigned short* __restrict__ Khi, unsigned short* __restrict__ Klo,
    unsigned short* __restrict__ vThi, unsigned short* __restrict__ vTlo)
{
    __shared__ unsigned short sAh[128 * 32], sAl[128 * 32];
    __shared__ unsigned short sBh[128 * 32], sBl[128 * 32];   // 32 KB

    const int t    = threadIdx.x;
    const int m0   = blockIdx.y * 128, n0 = blockIdx.x * 128;
    const int lane = t & 63, wave = t >> 6;
    const int lm   = lane & 15, quad = lane >> 4;
    const int wm   = (wave >> 1) * 64, wn = (wave & 1) * 64;

    const int lrow = lane >> 2, lcol = (lane & 3) * 8;
    const unsigned short* gAh = Ahi + (size_t)(m0 + wave * 32 + lrow) * D_ + lcol;
    const unsigned short* gAl = Alo + (size_t)(m0 + wave * 32 + lrow) * D_ + lcol;
    const unsigned short* gBh = BThi + (size_t)(n0 + wave * 32 + lrow) * D_ + lcol;
    const unsigned short* gBl = BTlo + (size_t)(n0 + wave * 32 + lrow) * D_ + lcol;
    const int ldst = wave * 1024 + lane * 8;   // u16 dest (= base + lane*16B)

    floatx4 acc[4][4];
#pragma unroll
    for (int i = 0; i < 4; i++)
#pragma unroll
        for (int j = 0; j < 4; j++)
#pragma unroll
            for (int r = 0; r < 4; r++) acc[i][j][r] = 0.f;

    for (int k0 = 0; k0 < D_; k0 += 32) {
        __syncthreads();   // readers of previous tile done
        dma16(gAh + k0, &sAh[ldst]);
        dma16(gAh + (size_t)16 * D_ + k0, &sAh[ldst + 512]);
        dma16(gAl + k0, &sAl[ldst]);
        dma16(gAl + (size_t)16 * D_ + k0, &sAl[ldst + 512]);
        dma16(gBh + k0, &sBh[ldst]);
        dma16(gBh + (size_t)16 * D_ + k0, &sBh[ldst + 512]);
        dma16(gBl + k0, &sBl[ldst]);
        dma16(gBl + (size_t)16 * D_ + k0, &sBl[ldst + 512]);
        __syncthreads();   // staged (compiler drains vmcnt(0) here)

        short8 bhf[4], blf[4];
#pragma unroll
        for (int nb = 0; nb < 4; nb++) {
            const int r = wn + nb * 16 + lm;
            bhf[nb] = *(const short8*)&sBh[r * 32 + quad * 8];
            blf[nb] = *(const short8*)&sBl[r * 32 + quad * 8];
        }
#pragma unroll
        for (int mb = 0; mb < 4; mb++) {
            const int r = wm + mb * 16 + lm;
            short8 ah = *(const short8*)&sAh[r * 32 + quad * 8];
            short8 al = *(const short8*)&sAl[r * 32 + quad * 8];
#pragma unroll
            for (int nb = 0; nb < 4; nb++) {
                acc[mb][nb] = __builtin_amdgcn_mfma_f32_16x16x32_bf16(ah, bhf[nb], acc[mb][nb], 0, 0, 0);
                acc[mb][nb] = __builtin_amdgcn_mfma_f32_16x16x32_bf16(al, bhf[nb], acc[mb][nb], 0, 0, 0);
                acc[mb][nb] = __builtin_amdgcn_mfma_f32_16x16x32_bf16(ah, blf[nb], acc[mb][nb], 0, 0, 0);
            }
        }
    }

    const int nmode = n0 >> 10;
    if (nmode == 0) {
#pragma unroll
        for (int nb = 0; nb < 4; nb++) {
            const int c = n0 + wn + nb * 16 + lm;
            const float bv = bias[c];
#pragma unroll
            for (int mb = 0; mb < 4; mb++) {
                const int rowb = m0 + wm + mb * 16 + quad * 4;
#pragma unroll
                for (int r = 0; r < 4; r++) {
                    unsigned short hh, ll;
                    split2((acc[mb][nb][r] + bv) * 0.125f, hh, ll);
                    Qhi[(size_t)(rowb + r) * D_ + c] = hh;
                    Qlo[(size_t)(rowb + r) * D_ + c] = ll;
                }
            }
        }
    } else if (nmode == 1) {
#pragma unroll
        for (int nb = 0; nb < 4; nb++) {
            const int c = n0 + wn + nb * 16 + lm;
            const float bv = bias[c];
            const int cq = c - 1024;
#pragma unroll
            for (int mb = 0; mb < 4; mb++) {
                const int rowb = m0 + wm + mb * 16 + quad * 4;
#pragma unroll
                for (int r = 0; r < 4; r++) {
                    unsigned short hh, ll;
                    split2(acc[mb][nb][r] + bv, hh, ll);
                    Khi[(size_t)(rowb + r) * D_ + cq] = hh;
                    Klo[(size_t)(rowb + r) * D_ + cq] = ll;
                }
            }
        }
    } else {
#pragma unroll
        for (int nb = 0; nb < 4; nb++) {
            const int c = n0 + wn + nb * 16 + lm;
            const float bv = bias[c];
            const int cq = c - 2048;
            const int hh_ = cq >> 6, dd = cq & 63;
#pragma unroll
            for (int mb = 0; mb < 4; mb++) {
                const int rowb = m0 + wm + mb * 16 + quad * 4;
                const int bb = rowb >> 11, ss = rowb & 2047;
                unsigned short hv[4], lv[4];
#pragma unroll
                for (int r = 0; r < 4; r++)
                    split2(acc[mb][nb][r] + bv, hv[r], lv[r]);
                const size_t idx = ((size_t)((bb * 16 + hh_) * 64 + dd)) * S_ + ss;
                *(uint2*)&vThi[idx] = make_uint2((unsigned)hv[0] | ((unsigned)hv[1] << 16),
                                                 (unsigned)hv[2] | ((unsigned)hv[3] << 16));
                *(uint2*)&vTlo[idx] = make_uint2((unsigned)lv[0] | ((unsigned)lv[1] << 16),
                                                 (unsigned)lv[2] | ((unsigned)lv[3] << 16));
            }
        }
    }
}

// ---------------------------------------------------------------------------
// Proj GEMM (R6-verified best): 64x64 tiles, 1024 blocks = 4/CU, 16 KB LDS,
// fully-DMA 2-barrier structure, XCD-chunk swizzle. Plain stores.
// ---------------------------------------------------------------------------
__global__ __launch_bounds__(256) void gemm_out(
    const unsigned short* __restrict__ Ahi, const unsigned short* __restrict__ Alo,
    const unsigned short* __restrict__ BThi, const unsigned short* __restrict__ BTlo,
    const float* __restrict__ bias, float* __restrict__ C)
{
    __shared__ unsigned short sAh[64 * 32], sAl[64 * 32];
    __shared__ unsigned short sBh[64 * 32], sBl[64 * 32];   // 16 KB

    const int t   = threadIdx.x;
    const int lid = blockIdx.x;                        // 0..1023
    const int swz = (lid & 7) * 128 + (lid >> 3);      // XCD-chunk, bijective
    const int bx  = swz & 15, by = swz >> 4;
    const int m0  = by * 64, n0 = bx * 64;
    const int lane = t & 63, wave = t >> 6;
    const int lm   = lane & 15, quad = lane >> 4;

    const int lrow = lane >> 2, lcol = (lane & 3) * 8;
    const unsigned short* gAh = Ahi + (size_t)(m0 + wave * 16 + lrow) * D_ + lcol;
    const unsigned short* gAl = Alo + (size_t)(m0 + wave * 16 + lrow) * D_ + lcol;
    const unsigned short* gBh = BThi + (size_t)(n0 + wave * 16 + lrow) * D_ + lcol;
    const unsigned short* gBl = BTlo + (size_t)(n0 + wave * 16 + lrow) * D_ + lcol;
    unsigned short* lAh = sAh + wave * 512 + lane * 8;
    unsigned short* lAl = sAl + wave * 512 + lane * 8;
    unsigned short* lBh = sBh + wave * 512 + lane * 8;
    unsigned short* lBl = sBl + wave * 512 + lane * 8;

    floatx4 acc[4];
#pragma unroll
    for (int j = 0; j < 4; j++)
#pragma unroll
        for (int r = 0; r < 4; r++) acc[j][r] = 0.f;

    for (int k0 = 0; k0 < D_; k0 += 32) {
        __syncthreads();
        dma16(gAh + k0, lAh);
        dma16(gAl + k0, lAl);
        dma16(gBh + k0, lBh);
        dma16(gBl + k0, lBl);
        __syncthreads();

        short8 ah = *(const short8*)&sAh[(wave * 16 + lm) * 32 + quad * 8];
        short8 al = *(const short8*)&sAl[(wave * 16 + lm) * 32 + quad * 8];
#pragma unroll
        for (int nb = 0; nb < 4; nb++) {
            short8 bh = *(const short8*)&sBh[(nb * 16 + lm) * 32 + quad * 8];
            short8 bl = *(const short8*)&sBl[(nb * 16 + lm) * 32 + quad * 8];
            acc[nb] = __builtin_amdgcn_mfma_f32_16x16x32_bf16(ah, bh, acc[nb], 0, 0, 0);
            acc[nb] = __builtin_amdgcn_mfma_f32_16x16x32_bf16(al, bh, acc[nb], 0, 0, 0);
            acc[nb] = __builtin_amdgcn_mfma_f32_16x16x32_bf16(ah, bl, acc[nb], 0, 0, 0);
        }
    }

#pragma unroll
    for (int nb = 0; nb < 4; nb++) {
        const int col = n0 + nb * 16 + lm;
        const float bv = bias[col];
#pragma unroll
        for (int r = 0; r < 4; r++) {
            const int row = m0 + wave * 16 + quad * 4 + r;
            C[(size_t)row * D_ + col] = acc[nb][r] + bv;
        }
    }
}

// ---------------------------------------------------------------------------
// MFMA flash attention v7: 128-row Q super-tile, 8 waves, DMA-staged
// XOR-swizzled K/V (as R9) + NEW XCD-chunked (b,h) mapping: each XCD owns
// 4 bh => K/V working set 4 MB = one L2 (was 32 MB -> L3-served staging).
// Load balance via (bh&1) qt-flip. All fragment math identical to R9.
// ---------------------------------------------------------------------------
#define PSP 72   // P row stride (64 data + 8 pad)

__global__ __launch_bounds__(512, 4) void flash_attn_mfma(
    unsigned short* QAhi, unsigned short* QAlo,   // Q in, attn out (aliased)
    const unsigned short* __restrict__ Khi, const unsigned short* __restrict__ Klo,
    const unsigned short* __restrict__ vThi, const unsigned short* __restrict__ vTlo)
{
    __shared__ unsigned short KhS[64 * 64], KlS[64 * 64];   // swizzled, 8 KB ea
    __shared__ unsigned short VhS[64 * 64], VlS[64 * 64];   // V^T tile [d][s]
    __shared__ unsigned short PhS[128 * PSP], PlS[128 * PSP]; // 68 KB total

    const int t    = threadIdx.x;           // 0..511
    // XCD-chunked remap: lid%8 = XCD; each XCD gets bh = 4*(lid&7)+..(4 bh)
    const int lid  = blockIdx.x + 16 * blockIdx.y;   // 0..511
    const int bh   = (lid & 7) * 4 + ((lid >> 3) & 3);
    const int pj   = lid >> 5;              // 0..15
    const int b    = bh >> 4, h = bh & 15;
    const int lane = t & 63, w = t >> 6;    // 8 waves
    const int lm   = lane & 15, quad = lane >> 4;

    const int qt = (bh & 1) ? (15 - pj) : pj;   // balance pairing
    const int q0 = qt * 128;
    const int ntiles = 2 * qt + 2;
    const int wdiag = (q0 >> 6) + (w >> 2);     // waves 0-3: 2qt; 4-7: 2qt+1

    // staging geometry: thread t covers row r0 = t>>3 (0..63), col-seg
    // inverse-swizzled so linear DMA lands swizzled (rule #21).
    const int r0  = t >> 3;                       // 0..63
    const int seg = (t & 7) ^ (r0 & 7);           // involution
    const unsigned short* gKh = Khi + (size_t)(b * S_ + r0) * D_ + h * HD + 8 * seg;
    const unsigned short* gKl = Klo + (size_t)(b * S_ + r0) * D_ + h * HD + 8 * seg;
    const unsigned short* gVh = vThi + ((size_t)((b * 16 + h) * 64 + r0)) * S_ + 8 * seg;
    const unsigned short* gVl = vTlo + ((size_t)((b * 16 + h) * 64 + r0)) * S_ + 8 * seg;
    const int ld0 = t * 8;                        // u16 dest (= base + t*16B)
    const int swzr = (lm & 7) << 3;               // read-side XOR (u16 units)

    // Q fragments (A-layout rows q0+16w+lm), pre-scaled by 1/8
    short8 qh[2], ql[2];
    {
        const size_t qoff = (size_t)(b * S_ + q0 + 16 * w + lm) * D_ + h * HD + quad * 8;
        qh[0] = *(const short8*)&QAhi[qoff];
        qh[1] = *(const short8*)&QAhi[qoff + 32];
        ql[0] = *(const short8*)&QAlo[qoff];
        ql[1] = *(const short8*)&QAlo[qoff + 32];
    }

    float lsum[4] = {0.f, 0.f, 0.f, 0.f};
    floatx4 o[4];
#pragma unroll
    for (int nb = 0; nb < 4; nb++)
#pragma unroll
        for (int r = 0; r < 4; r++) o[nb][r] = 0.f;

    for (int kt = 0; kt < ntiles; kt++) {
        __syncthreads();   // all waves done reading previous tile
        {
            const size_t ko = (size_t)(kt * 64) * D_;
            const int vo = kt * 64;
            dma16(gKh + ko, &KhS[ld0]);
            dma16(gKl + ko, &KlS[ld0]);
            dma16(gVh + vo, &VhS[ld0]);
            dma16(gVl + vo, &VlS[ld0]);
        }
        __syncthreads();   // DMA drained (vmcnt0 at barrier)

        if (kt <= wdiag) {   // wave-uniform causal skip
            // ---- S = Q K^T (3-MFMA split), swizzled K reads
            floatx4 sa[4];
#pragma unroll
            for (int nb = 0; nb < 4; nb++)
#pragma unroll
                for (int r = 0; r < 4; r++) sa[nb][r] = 0.f;
            __builtin_amdgcn_s_setprio(1);
#pragma unroll
            for (int s = 0; s < 2; s++) {
#pragma unroll
                for (int nb = 0; nb < 4; nb++) {
                    const int ka = (nb * 16 + lm) * 64 + ((s * 32 + quad * 8) ^ swzr);
                    short8 kh = *(const short8*)&KhS[ka];
                    short8 kl = *(const short8*)&KlS[ka];
                    sa[nb] = __builtin_amdgcn_mfma_f32_16x16x32_bf16(qh[s], kh, sa[nb], 0, 0, 0);
                    sa[nb] = __builtin_amdgcn_mfma_f32_16x16x32_bf16(ql[s], kh, sa[nb], 0, 0, 0);
                    sa[nb] = __builtin_amdgcn_mfma_f32_16x16x32_bf16(qh[s], kl, sa[nb], 0, 0, 0);
                }
            }
            __builtin_amdgcn_s_setprio(0);

            // ---- softmax-lite (no shift); mask only on the diag tile
            const bool diag = (kt == wdiag);
            const int kbase = kt * 64;
#pragma unroll
            for (int r = 0; r < 4; r++) {
                const int qabs = q0 + 16 * w + 4 * quad + r;
                const int rloc = 16 * w + 4 * quad + r;
#pragma unroll
                for (int nb = 0; nb < 4; nb++) {
                    float p = __expf(sa[nb][r]);
                    if (diag && (kbase + 16 * nb + lm > qabs)) p = 0.f;
                    lsum[r] += p;
                    unsigned short hh, ll;
                    split2(p, hh, ll);
                    PhS[rloc * PSP + 16 * nb + lm] = hh;
                    PlS[rloc * PSP + 16 * nb + lm] = ll;
                }
            }

            // ---- O += P V (same-wave P rows; swizzled V reads)
            __builtin_amdgcn_s_setprio(1);
#pragma unroll
            for (int ks = 0; ks < 2; ks++) {
                short8 pf = *(const short8*)&PhS[(16 * w + lm) * PSP + ks * 32 + quad * 8];
                short8 pg = *(const short8*)&PlS[(16 * w + lm) * PSP + ks * 32 + quad * 8];
#pragma unroll
                for (int nb = 0; nb < 4; nb++) {
                    const int va = (nb * 16 + lm) * 64 + ((ks * 32 + quad * 8) ^ swzr);
                    short8 vhf = *(const short8*)&VhS[va];
                    short8 vlf = *(const short8*)&VlS[va];
                    o[nb] = __builtin_amdgcn_mfma_f32_16x16x32_bf16(pf, vhf, o[nb], 0, 0, 0);
                    o[nb] = __builtin_amdgcn_mfma_f32_16x16x32_bf16(pg, vhf, o[nb], 0, 0, 0);
                    o[nb] = __builtin_amdgcn_mfma_f32_16x16x32_bf16(pf, vlf, o[nb], 0, 0, 0);
                }
            }
            __builtin_amdgcn_s_setprio(0);
        }
    }

    // epilogue: reduce l, normalize, write attn PRE-SPLIT into Q buffers
#pragma unroll
    for (int r = 0; r < 4; r++) {
        float l = lsum[r];
        l += __shfl_xor(l, 1);
        l += __shfl_xor(l, 2);
        l += __shfl_xor(l, 4);
        l += __shfl_xor(l, 8);
        const float inv = 1.f / l;
        const size_t rowoff =
            (size_t)(b * S_ + q0 + 16 * w + 4 * quad + r) * D_ + h * HD + lm;
#pragma unroll
        for (int nb = 0; nb < 4; nb++) {
            unsigned short hh, ll;
            split2(o[nb][r] * inv, hh, ll);
            QAhi[rowoff + 16 * nb] = hh;
            QAlo[rowoff + 16 * nb] = ll;
        }
    }
}

// ---------------------------------------------------------------------------
extern "C" void kernel_launch(void* const* d_in, const int* in_sizes, int n_in,
                              void* d_out, int out_size, void* d_ws, size_t ws_size,
                              hipStream_t stream)
{
    const float* hs     = (const float*)d_in[0];
    const float* attn_w = (const float*)d_in[1];
    const float* attn_b = (const float*)d_in[2];
    const float* proj_w = (const float*)d_in[3];
    const float* proj_b = (const float*)d_in[4];
    float* outp = (float*)d_out;

    const size_t QE = (size_t)M_ * D_;          // 4,194,304
    const size_t WQ = (size_t)D_ * N_QKV;       // 3,145,728
    unsigned short* Qhi   = (unsigned short*)d_ws;       // also attn hi
    unsigned short* Qlo   = Qhi + QE;                    // also attn lo
    unsigned short* Khi   = Qlo + QE;
    unsigned short* Klo   = Khi + QE;
    unsigned short* vThi  = Klo + QE;
    unsigned short* vTlo  = vThi + QE;
    unsigned short* WqThi = vTlo + QE;
    unsigned short* WqTlo = WqThi + WQ;
    unsigned short* WpThi = WqTlo + WQ;
    unsigned short* WpTlo = WpThi + (size_t)D_ * D_;
    unsigned short* Ahi   = WpTlo + (size_t)D_ * D_;     // hs pre-split
    unsigned short* Alo   = Ahi + QE;                    // total = 80 MB

    dim3 blk(256);
    prep_all<<<dim3(3072), blk, 0, stream>>>(
        hs, attn_w, proj_w, Ahi, Alo, WqThi, WqTlo, WpThi, WpTlo);
    gemm_qkv<<<dim3(N_QKV / 128, M_ / 128), blk, 0, stream>>>(
        Ahi, Alo, WqThi, WqTlo, attn_b, Qhi, Qlo, Khi, Klo, vThi, vTlo);
    flash_attn_mfma<<<dim3(16, B_ * H_), dim3(512), 0, stream>>>(
        Qhi, Qlo, Khi, Klo, vThi, vTlo);
    gemm_out<<<dim3(1024), blk, 0, stream>>>(
        Qhi, Qlo, WpThi, WpTlo, proj_b, outp);
}

// Round 11
// 299.117 us; speedup vs baseline: 1.0592x; 1.0092x over previous
//
#include <hip/hip_runtime.h>
#include <hip/hip_bf16.h>
#include <math.h>

#define B_ 2
#define S_ 2048
#define D_ 1024
#define H_ 16
#define HD 64
#define M_ (B_ * S_)     // 4096
#define N_QKV (3 * D_)   // 3072
#define LOG2E_8 0.18033688011112042f   // log2(e)/8: Q pre-scale so flash uses exp2

typedef short short8 __attribute__((ext_vector_type(8)));
typedef float floatx4 __attribute__((ext_vector_type(4)));

// HW RNE f32->bf16 (compiler emits v_cvt_pk_bf16_f32)
static __device__ __forceinline__ unsigned short f2bf(float x) {
    __hip_bfloat16 h = __float2bfloat16(x);
    unsigned short u;
    __builtin_memcpy(&u, &h, sizeof(u));
    return u;
}
static __device__ __forceinline__ float bf2f(unsigned short b) {
    union { unsigned u; float f; } v; v.u = ((unsigned)b) << 16;
    return v.f;
}
// RNE split: x = hi + lo + eps, |eps| ~ 2^-17 |x|
static __device__ __forceinline__ void split2(float x, unsigned short& h, unsigned short& l) {
    h = f2bf(x);
    l = f2bf(x - bf2f(h));
}

// async global->LDS DMA, 16 B per lane (dest = wave-uniform base + lane*16)
static __device__ __forceinline__ void dma16(const void* g, void* l) {
    __builtin_amdgcn_global_load_lds(
        (const __attribute__((address_space(1))) unsigned int*)g,
        (__attribute__((address_space(3))) unsigned int*)l,
        16, 0, 0);
}

// ---------------------------------------------------------------------------
// prep_all (R10-verified): ONE dispatch for all preprocessing.
//   blocks [0, 2048):        hs fp32 -> Ahi/Alo bf16 (elementwise)
//   blocks [2048, 2816):     attn_w -> WqT hi/lo
//   blocks [2816, 3072):     proj_w -> WpT hi/lo
// ---------------------------------------------------------------------------
__global__ __launch_bounds__(256) void prep_all(
    const float* __restrict__ hs,
    const float* __restrict__ attn_w,
    const float* __restrict__ proj_w,
    unsigned short* __restrict__ Ahi, unsigned short* __restrict__ Alo,
    unsigned short* __restrict__ WqThi, unsigned short* __restrict__ WqTlo,
    unsigned short* __restrict__ WpThi, unsigned short* __restrict__ WpTlo)
{
    __shared__ float Ws[64][68];
    const int bid = blockIdx.x;
    const int t   = threadIdx.x;

    if (bid < 2048) {   // ---- elementwise A split
        const size_t i = ((size_t)bid * 256 + t) * 8;
        float4 a = *(const float4*)(hs + i);
        float4 b = *(const float4*)(hs + i + 4);
        float xs[8] = {a.x, a.y, a.z, a.w, b.x, b.y, b.z, b.w};
        short8 h, l;
#pragma unroll
        for (int e = 0; e < 8; e++) {
            unsigned short hh, ll;
            split2(xs[e], hh, ll);
            h[e] = (short)hh; l[e] = (short)ll;
        }
        *(short8*)&Ahi[i] = h;
        *(short8*)&Alo[i] = l;
        return;
    }

    // ---- weight transpose+split sections
    const float* W; unsigned short *Thi, *Tlo; int N, n0, k0;
    if (bid < 2816) {
        const int s = bid - 2048;            // 0..767 = 48 x 16
        W = attn_w; Thi = WqThi; Tlo = WqTlo; N = N_QKV;
        n0 = (s % 48) * 64; k0 = (s / 48) * 64;
    } else {
        const int s = bid - 2816;            // 0..255 = 16 x 16
        W = proj_w; Thi = WpThi; Tlo = WpTlo; N = D_;
        n0 = (s % 16) * 64; k0 = (s / 16) * 64;
    }
    {
        const int kl = t >> 4, nl = (t & 15) * 4;
        const float* src = W + (size_t)(k0 + kl) * N + n0 + nl;
#pragma unroll
        for (int g = 0; g < 4; g++)
            *(float4*)&Ws[kl + g * 16][nl] = *(const float4*)(src + (size_t)g * 16 * N);
    }
    __syncthreads();
    {
        const int nl = t >> 2, ks = (t & 3) * 16;
        short8 h0, h1, l0, l1;
#pragma unroll
        for (int j = 0; j < 8; j++) {
            unsigned short hh, ll;
            split2(Ws[ks + j][nl], hh, ll);
            h0[j] = (short)hh; l0[j] = (short)ll;
        }
#pragma unroll
        for (int j = 0; j < 8; j++) {
            unsigned short hh, ll;
            split2(Ws[ks + 8 + j][nl], hh, ll);
            h1[j] = (short)hh; l1[j] = (short)ll;
        }
        unsigned short* dh = Thi + (size_t)(n0 + nl) * D_ + k0 + ks;
        unsigned short* dl = Tlo + (size_t)(n0 + nl) * D_ + k0 + ks;
        *(short8*)dh = h0; *(short8*)(dh + 8) = h1;
        *(short8*)dl = l0; *(short8*)(dl + 8) = l1;
    }
}

// ---------------------------------------------------------------------------
// QKV GEMM (unchanged structure, measured ~107 us): m97 structure, 128x128
// tile, single 32KB buffer, fully-DMA staging, zero K-loop VALU.
// Q epilogue scale is now log2(e)/8 so flash uses native exp2.
// ---------------------------------------------------------------------------
__global__ __launch_bounds__(256) void gemm_qkv(
    const unsigned short* __restrict__ Ahi, const unsigned short* __restrict__ Alo,
    const unsigned short* __restrict__ BThi, const unsigned short* __restrict__ BTlo,
    const float* __restrict__ bias,
    unsigned short* __restrict__ Qhi, unsigned short* __restrict__ Qlo,
    unsigned short* __restrict__ Khi, unsigned short* __restrict__ Klo,
    unsigned short* __restrict__ vThi, unsigned short* __restrict__ vTlo)
{
    __shared__ unsigned short sAh[128 * 32], sAl[128 * 32];
    __shared__ unsigned short sBh[128 * 32], sBl[128 * 32];   // 32 KB

    const int t    = threadIdx.x;
    const int m0   = blockIdx.y * 128, n0 = blockIdx.x * 128;
    const int lane = t & 63, wave = t >> 6;
    const int lm   = lane & 15, quad = lane >> 4;
    const int wm   = (wave >> 1) * 64, wn = (wave & 1) * 64;

    const int lrow = lane >> 2, lcol = (lane & 3) * 8;
    const unsigned short* gAh = Ahi + (size_t)(m0 + wave * 32 + lrow) * D_ + lcol;
    const unsigned short* gAl = Alo + (size_t)(m0 + wave * 32 + lrow) * D_ + lcol;
    const unsigned short* gBh = BThi + (size_t)(n0 + wave * 32 + lrow) * D_ + lcol;
    const unsigned short* gBl = BTlo + (size_t)(n0 + wave * 32 + lrow) * D_ + lcol;
    const int ldst = wave * 1024 + lane * 8;   // u16 dest (= base + lane*16B)

    floatx4 acc[4][4];
#pragma unroll
    for (int i = 0; i < 4; i++)
#pragma unroll
        for (int j = 0; j < 4; j++)
#pragma unroll
            for (int r = 0; r < 4; r++) acc[i][j][r] = 0.f;

    for (int k0 = 0; k0 < D_; k0 += 32) {
        __syncthreads();   // readers of previous tile done
        dma16(gAh + k0, &sAh[ldst]);
        dma16(gAh + (size_t)16 * D_ + k0, &sAh[ldst + 512]);
        dma16(gAl + k0, &sAl[ldst]);
        dma16(gAl + (size_t)16 * D_ + k0, &sAl[ldst + 512]);
        dma16(gBh + k0, &sBh[ldst]);
        dma16(gBh + (size_t)16 * D_ + k0, &sBh[ldst + 512]);
        dma16(gBl + k0, &sBl[ldst]);
        dma16(gBl + (size_t)16 * D_ + k0, &sBl[ldst + 512]);
        __syncthreads();   // staged (compiler drains vmcnt(0) here)

        short8 bhf[4], blf[4];
#pragma unroll
        for (int nb = 0; nb < 4; nb++) {
            const int r = wn + nb * 16 + lm;
            bhf[nb] = *(const short8*)&sBh[r * 32 + quad * 8];
            blf[nb] = *(const short8*)&sBl[r * 32 + quad * 8];
        }
#pragma unroll
        for (int mb = 0; mb < 4; mb++) {
            const int r = wm + mb * 16 + lm;
            short8 ah = *(const short8*)&sAh[r * 32 + quad * 8];
            short8 al = *(const short8*)&sAl[r * 32 + quad * 8];
#pragma unroll
            for (int nb = 0; nb < 4; nb++) {
                acc[mb][nb] = __builtin_amdgcn_mfma_f32_16x16x32_bf16(ah, bhf[nb], acc[mb][nb], 0, 0, 0);
                acc[mb][nb] = __builtin_amdgcn_mfma_f32_16x16x32_bf16(al, bhf[nb], acc[mb][nb], 0, 0, 0);
                acc[mb][nb] = __builtin_amdgcn_mfma_f32_16x16x32_bf16(ah, blf[nb], acc[mb][nb], 0, 0, 0);
            }
        }
    }

    const int nmode = n0 >> 10;
    if (nmode == 0) {
#pragma unroll
        for (int nb = 0; nb < 4; nb++) {
            const int c = n0 + wn + nb * 16 + lm;
            const float bv = bias[c];
#pragma unroll
            for (int mb = 0; mb < 4; mb++) {
                const int rowb = m0 + wm + mb * 16 + quad * 4;
#pragma unroll
                for (int r = 0; r < 4; r++) {
                    unsigned short hh, ll;
                    split2((acc[mb][nb][r] + bv) * LOG2E_8, hh, ll);
                    Qhi[(size_t)(rowb + r) * D_ + c] = hh;
                    Qlo[(size_t)(rowb + r) * D_ + c] = ll;
                }
            }
        }
    } else if (nmode == 1) {
#pragma unroll
        for (int nb = 0; nb < 4; nb++) {
            const int c = n0 + wn + nb * 16 + lm;
            const float bv = bias[c];
            const int cq = c - 1024;
#pragma unroll
            for (int mb = 0; mb < 4; mb++) {
                const int rowb = m0 + wm + mb * 16 + quad * 4;
#pragma unroll
                for (int r = 0; r < 4; r++) {
                    unsigned short hh, ll;
                    split2(acc[mb][nb][r] + bv, hh, ll);
                    Khi[(size_t)(rowb + r) * D_ + cq] = hh;
                    Klo[(size_t)(rowb + r) * D_ + cq] = ll;
                }
            }
        }
    } else {
#pragma unroll
        for (int nb = 0; nb < 4; nb++) {
            const int c = n0 + wn + nb * 16 + lm;
            const float bv = bias[c];
            const int cq = c - 2048;
            const int hh_ = cq >> 6, dd = cq & 63;
#pragma unroll
            for (int mb = 0; mb < 4; mb++) {
                const int rowb = m0 + wm + mb * 16 + quad * 4;
                const int bb = rowb >> 11, ss = rowb & 2047;
                unsigned short hv[4], lv[4];
#pragma unroll
                for (int r = 0; r < 4; r++)
                    split2(acc[mb][nb][r] + bv, hv[r], lv[r]);
                const size_t idx = ((size_t)((bb * 16 + hh_) * 64 + dd)) * S_ + ss;
                *(uint2*)&vThi[idx] = make_uint2((unsigned)hv[0] | ((unsigned)hv[1] << 16),
                                                 (unsigned)hv[2] | ((unsigned)hv[3] << 16));
                *(uint2*)&vTlo[idx] = make_uint2((unsigned)lv[0] | ((unsigned)lv[1] << 16),
                                                 (unsigned)lv[2] | ((unsigned)lv[3] << 16));
            }
        }
    }
}

// ---------------------------------------------------------------------------
// Proj GEMM v2: 64x64 tiles, BK=64 (HALF the barriers of R6; occupancy
// unchanged: grid caps 4 blocks/CU, 32 KB LDS admits 5). Rows are 128 B so
// reads use the flash-v5-verified both-sides XOR swizzle (rule #21: linear
// DMA dest + inverse-swizzled global source seg=(t&7)^((t>>3)&7) + chunk^
// (lm&7) reads) -> ~2-way conflicts. XCD-chunk block swizzle kept.
// ---------------------------------------------------------------------------
__global__ __launch_bounds__(256) void gemm_out(
    const unsigned short* __restrict__ Ahi, const unsigned short* __restrict__ Alo,
    const unsigned short* __restrict__ BThi, const unsigned short* __restrict__ BTlo,
    const float* __restrict__ bias, float* __restrict__ C)
{
    __shared__ unsigned short sAh[64 * 64], sAl[64 * 64];
    __shared__ unsigned short sBh[64 * 64], sBl[64 * 64];   // 32 KB

    const int t   = threadIdx.x;
    const int lid = blockIdx.x;                        // 0..1023
    const int swz = (lid & 7) * 128 + (lid >> 3);      // XCD-chunk, bijective
    const int bx  = swz & 15, by = swz >> 4;
    const int m0  = by * 64, n0 = bx * 64;
    const int lane = t & 63, wave = t >> 6;
    const int lm   = lane & 15, quad = lane >> 4;

    // staging: thread t, chunk c in {0,1}: LDS row (t>>3)+32c, colseg t&7;
    // global colseg inverse-swizzled so linear DMA lands swizzled.
    const int r0   = t >> 3;                  // 0..31
    const int gseg = (t & 7) ^ (r0 & 7);      // involution ((r0+32)&7 == r0&7)
    const unsigned short* gAh = Ahi + (size_t)(m0 + r0) * D_ + gseg * 8;
    const unsigned short* gAl = Alo + (size_t)(m0 + r0) * D_ + gseg * 8;
    const unsigned short* gBh = BThi + (size_t)(n0 + r0) * D_ + gseg * 8;
    const unsigned short* gBl = BTlo + (size_t)(n0 + r0) * D_ + gseg * 8;
    const int ld0  = t * 8;                   // chunk0 dest; chunk1 at +2048
    const int swzr = lm & 7;                  // read-side chunk XOR

    floatx4 acc[4];
#pragma unroll
    for (int j = 0; j < 4; j++)
#pragma unroll
        for (int r = 0; r < 4; r++) acc[j][r] = 0.f;

    for (int k0 = 0; k0 < D_; k0 += 64) {
        __syncthreads();
        dma16(gAh + k0, &sAh[ld0]);
        dma16(gAh + (size_t)32 * D_ + k0, &sAh[ld0 + 2048]);
        dma16(gAl + k0, &sAl[ld0]);
        dma16(gAl + (size_t)32 * D_ + k0, &sAl[ld0 + 2048]);
        dma16(gBh + k0, &sBh[ld0]);
        dma16(gBh + (size_t)32 * D_ + k0, &sBh[ld0 + 2048]);
        dma16(gBl + k0, &sBl[ld0]);
        dma16(gBl + (size_t)32 * D_ + k0, &sBl[ld0 + 2048]);
        __syncthreads();

#pragma unroll
        for (int ks = 0; ks < 2; ks++) {
            const int arow = (wave * 16 + lm) * 64 + (((ks * 4 + quad) ^ swzr) * 8);
            short8 ah = *(const short8*)&sAh[arow];
            short8 al = *(const short8*)&sAl[arow];
#pragma unroll
            for (int nb = 0; nb < 4; nb++) {
                const int brow = (nb * 16 + lm) * 64 + (((ks * 4 + quad) ^ swzr) * 8);
                short8 bh = *(const short8*)&sBh[brow];
                short8 bl = *(const short8*)&sBl[brow];
                acc[nb] = __builtin_amdgcn_mfma_f32_16x16x32_bf16(ah, bh, acc[nb], 0, 0, 0);
                acc[nb] = __builtin_amdgcn_mfma_f32_16x16x32_bf16(al, bh, acc[nb], 0, 0, 0);
                acc[nb] = __builtin_amdgcn_mfma_f32_16x16x32_bf16(ah, bl, acc[nb], 0, 0, 0);
            }
        }
    }

#pragma unroll
    for (int nb = 0; nb < 4; nb++) {
        const int col = n0 + nb * 16 + lm;
        const float bv = bias[col];
#pragma unroll
        for (int r = 0; r < 4; r++) {
            const int row = m0 + wave * 16 + quad * 4 + r;
            C[(size_t)row * D_ + col] = acc[nb][r] + bv;
        }
    }
}

// ---------------------------------------------------------------------------
// MFMA flash attention v7 (R10-verified) + exp2: 128-row Q super-tile,
// 8 waves, DMA-staged XOR-swizzled K/V, XCD-chunked (b,h) mapping (each XCD
// owns 4 bh = 4 MB K/V = one L2). Q pre-scaled by log2e/8 so p = exp2(sa)
// is one native v_exp_f32 (no hidden mul).
// ---------------------------------------------------------------------------
#define PSP 72   // P row stride (64 data + 8 pad)

__global__ __launch_bounds__(512, 4) void flash_attn_mfma(
    unsigned short* QAhi, unsigned short* QAlo,   // Q in, attn out (aliased)
    const unsigned short* __restrict__ Khi, const unsigned short* __restrict__ Klo,
    const unsigned short* __restrict__ vThi, const unsigned short* __restrict__ vTlo)
{
    __shared__ unsigned short KhS[64 * 64], KlS[64 * 64];   // swizzled, 8 KB ea
    __shared__ unsigned short VhS[64 * 64], VlS[64 * 64];   // V^T tile [d][s]
    __shared__ unsigned short PhS[128 * PSP], PlS[128 * PSP]; // 68 KB total

    const int t    = threadIdx.x;           // 0..511
    // XCD-chunked remap: lid%8 = XCD; each XCD gets 4 bh
    const int lid  = blockIdx.x + 16 * blockIdx.y;   // 0..511
    const int bh   = (lid & 7) * 4 + ((lid >> 3) & 3);
    const int pj   = lid >> 5;              // 0..15
    const int b    = bh >> 4, h = bh & 15;
    const int lane = t & 63, w = t >> 6;    // 8 waves
    const int lm   = lane & 15, quad = lane >> 4;

    const int qt = (bh & 1) ? (15 - pj) : pj;   // balance pairing
    const int q0 = qt * 128;
    const int ntiles = 2 * qt + 2;
    const int wdiag = (q0 >> 6) + (w >> 2);     // waves 0-3: 2qt; 4-7: 2qt+1

    // staging geometry (rule #21): linear DMA dest + inverse-swizzled source
    const int r0  = t >> 3;                       // 0..63
    const int seg = (t & 7) ^ (r0 & 7);           // involution
    const unsigned short* gKh = Khi + (size_t)(b * S_ + r0) * D_ + h * HD + 8 * seg;
    const unsigned short* gKl = Klo + (size_t)(b * S_ + r0) * D_ + h * HD + 8 * seg;
    const unsigned short* gVh = vThi + ((size_t)((b * 16 + h) * 64 + r0)) * S_ + 8 * seg;
    const unsigned short* gVl = vTlo + ((size_t)((b * 16 + h) * 64 + r0)) * S_ + 8 * seg;
    const int ld0 = t * 8;                        // u16 dest (= base + t*16B)
    const int swzr = (lm & 7) << 3;               // read-side XOR (u16 units)

    // Q fragments (A-layout rows q0+16w+lm), pre-scaled by log2e/8
    short8 qh[2], ql[2];
    {
        const size_t qoff = (size_t)(b * S_ + q0 + 16 * w + lm) * D_ + h * HD + quad * 8;
        qh[0] = *(const short8*)&QAhi[qoff];
        qh[1] = *(const short8*)&QAhi[qoff + 32];
        ql[0] = *(const short8*)&QAlo[qoff];
        ql[1] = *(const short8*)&QAlo[qoff + 32];
    }

    float lsum[4] = {0.f, 0.f, 0.f, 0.f};
    floatx4 o[4];
#pragma unroll
    for (int nb = 0; nb < 4; nb++)
#pragma unroll
        for (int r = 0; r < 4; r++) o[nb][r] = 0.f;

    for (int kt = 0; kt < ntiles; kt++) {
        __syncthreads();   // all waves done reading previous tile
        {
            const size_t ko = (size_t)(kt * 64) * D_;
            const int vo = kt * 64;
            dma16(gKh + ko, &KhS[ld0]);
            dma16(gKl + ko, &KlS[ld0]);
            dma16(gVh + vo, &VhS[ld0]);
            dma16(gVl + vo, &VlS[ld0]);
        }
        __syncthreads();   // DMA drained (vmcnt0 at barrier)

        if (kt <= wdiag) {   // wave-uniform causal skip
            // ---- S = Q K^T (3-MFMA split), swizzled K reads
            floatx4 sa[4];
#pragma unroll
            for (int nb = 0; nb < 4; nb++)
#pragma unroll
                for (int r = 0; r < 4; r++) sa[nb][r] = 0.f;
            __builtin_amdgcn_s_setprio(1);
#pragma unroll
            for (int s = 0; s < 2; s++) {
#pragma unroll
                for (int nb = 0; nb < 4; nb++) {
                    const int ka = (nb * 16 + lm) * 64 + ((s * 32 + quad * 8) ^ swzr);
                    short8 kh = *(const short8*)&KhS[ka];
                    short8 kl = *(const short8*)&KlS[ka];
                    sa[nb] = __builtin_amdgcn_mfma_f32_16x16x32_bf16(qh[s], kh, sa[nb], 0, 0, 0);
                    sa[nb] = __builtin_amdgcn_mfma_f32_16x16x32_bf16(ql[s], kh, sa[nb], 0, 0, 0);
                    sa[nb] = __builtin_amdgcn_mfma_f32_16x16x32_bf16(qh[s], kl, sa[nb], 0, 0, 0);
                }
            }
            __builtin_amdgcn_s_setprio(0);

            // ---- softmax-lite (no shift); mask only on the diag tile
            const bool diag = (kt == wdiag);
            const int kbase = kt * 64;
#pragma unroll
            for (int r = 0; r < 4; r++) {
                const int qabs = q0 + 16 * w + 4 * quad + r;
                const int rloc = 16 * w + 4 * quad + r;
#pragma unroll
                for (int nb = 0; nb < 4; nb++) {
                    float p = exp2f(sa[nb][r]);   // native v_exp_f32
                    if (diag && (kbase + 16 * nb + lm > qabs)) p = 0.f;
                    lsum[r] += p;
                    unsigned short hh, ll;
                    split2(p, hh, ll);
                    PhS[rloc * PSP + 16 * nb + lm] = hh;
                    PlS[rloc * PSP + 16 * nb + lm] = ll;
                }
            }

            // ---- O += P V (same-wave P rows; swizzled V reads)
            __builtin_amdgcn_s_setprio(1);
#pragma unroll
            for (int ks = 0; ks < 2; ks++) {
                short8 pf = *(const short8*)&PhS[(16 * w + lm) * PSP + ks * 32 + quad * 8];
                short8 pg = *(const short8*)&PlS[(16 * w + lm) * PSP + ks * 32 + quad * 8];
#pragma unroll
                for (int nb = 0; nb < 4; nb++) {
                    const int va = (nb * 16 + lm) * 64 + ((ks * 32 + quad * 8) ^ swzr);
                    short8 vhf = *(const short8*)&VhS[va];
                    short8 vlf = *(const short8*)&VlS[va];
                    o[nb] = __builtin_amdgcn_mfma_f32_16x16x32_bf16(pf, vhf, o[nb], 0, 0, 0);
                    o[nb] = __builtin_amdgcn_mfma_f32_16x16x32_bf16(pg, vhf, o[nb], 0, 0, 0);
                    o[nb] = __builtin_amdgcn_mfma_f32_16x16x32_bf16(pf, vlf, o[nb], 0, 0, 0);
                }
            }
            __builtin_amdgcn_s_setprio(0);
        }
    }

    // epilogue: reduce l, normalize, write attn PRE-SPLIT into Q buffers
#pragma unroll
    for (int r = 0; r < 4; r++) {
        float l = lsum[r];
        l += __shfl_xor(l, 1);
        l += __shfl_xor(l, 2);
        l += __shfl_xor(l, 4);
        l += __shfl_xor(l, 8);
        const float inv = 1.f / l;
        const size_t rowoff =
            (size_t)(b * S_ + q0 + 16 * w + 4 * quad + r) * D_ + h * HD + lm;
#pragma unroll
        for (int nb = 0; nb < 4; nb++) {
            unsigned short hh, ll;
            split2(o[nb][r] * inv, hh, ll);
            QAhi[rowoff + 16 * nb] = hh;
            QAlo[rowoff + 16 * nb] = ll;
        }
    }
}

// ---------------------------------------------------------------------------
extern "C" void kernel_launch(void* const* d_in, const int* in_sizes, int n_in,
                              void* d_out, int out_size, void* d_ws, size_t ws_size,
                              hipStream_t stream)
{
    const float* hs     = (const float*)d_in[0];
    const float* attn_w = (const float*)d_in[1];
    const float* attn_b = (const float*)d_in[2];
    const float* proj_w = (const float*)d_in[3];
    const float* proj_b = (const float*)d_in[4];
    float* outp = (float*)d_out;

    const size_t QE = (size_t)M_ * D_;          // 4,194,304
    const size_t WQ = (size_t)D_ * N_QKV;       // 3,145,728
    unsigned short* Qhi   = (unsigned short*)d_ws;       // also attn hi
    unsigned short* Qlo   = Qhi + QE;                    // also attn lo
    unsigned short* Khi   = Qlo + QE;
    unsigned short* Klo   = Khi + QE;
    unsigned short* vThi  = Klo + QE;
    unsigned short* vTlo  = vThi + QE;
    unsigned short* WqThi = vTlo + QE;
    unsigned short* WqTlo = WqThi + WQ;
    unsigned short* WpThi = WqTlo + WQ;
    unsigned short* WpTlo = WpThi + (size_t)D_ * D_;
    unsigned short* Ahi   = WpTlo + (size_t)D_ * D_;     // hs pre-split
    unsigned short* Alo   = Ahi + QE;                    // total = 80 MB

    dim3 blk(256);
    prep_all<<<dim3(3072), blk, 0, stream>>>(
        hs, attn_w, proj_w, Ahi, Alo, WqThi, WqTlo, WpThi, WpTlo);
    gemm_qkv<<<dim3(N_QKV / 128, M_ / 128), blk, 0, stream>>>(
        Ahi, Alo, WqThi, WqTlo, attn_b, Qhi, Qlo, Khi, Klo, vThi, vTlo);
    flash_attn_mfma<<<dim3(16, B_ * H_), dim3(512), 0, stream>>>(
        Qhi, Qlo, Khi, Klo, vThi, vTlo);
    gemm_out<<<dim3(1024), blk, 0, stream>>>(
        Qhi, Qlo, WpThi, WpTlo, proj_b, outp);
}

// Round 12
// 297.652 us; speedup vs baseline: 1.0644x; 1.0049x over previous
//
#include <hip/hip_runtime.h>
#include <hip/hip_bf16.h>
#include <math.h>

#define B_ 2
#define S_ 2048
#define D_ 1024
#define H_ 16
#define HD 64
#define M_ (B_ * S_)     // 4096
#define N_QKV (3 * D_)   // 3072
#define LOG2E_8 0.18033688011112042f   // log2(e)/8: Q pre-scale so flash uses exp2

typedef short short8 __attribute__((ext_vector_type(8)));
typedef float floatx4 __attribute__((ext_vector_type(4)));

// HW RNE f32->bf16 (compiler emits v_cvt_pk_bf16_f32)
static __device__ __forceinline__ unsigned short f2bf(float x) {
    __hip_bfloat16 h = __float2bfloat16(x);
    unsigned short u;
    __builtin_memcpy(&u, &h, sizeof(u));
    return u;
}
static __device__ __forceinline__ float bf2f(unsigned short b) {
    union { unsigned u; float f; } v; v.u = ((unsigned)b) << 16;
    return v.f;
}
// RNE split: x = hi + lo + eps, |eps| ~ 2^-17 |x|
static __device__ __forceinline__ void split2(float x, unsigned short& h, unsigned short& l) {
    h = f2bf(x);
    l = f2bf(x - bf2f(h));
}

// async global->LDS DMA, 16 B per lane (dest = wave-uniform base + lane*16)
static __device__ __forceinline__ void dma16(const void* g, void* l) {
    __builtin_amdgcn_global_load_lds(
        (const __attribute__((address_space(1))) unsigned int*)g,
        (__attribute__((address_space(3))) unsigned int*)l,
        16, 0, 0);
}

// ---------------------------------------------------------------------------
// prep_all (R10-verified): ONE dispatch for all preprocessing.
//   blocks [0, 2048):        hs fp32 -> Ahi/Alo bf16 (elementwise)
//   blocks [2048, 2816):     attn_w -> WqT hi/lo
//   blocks [2816, 3072):     proj_w -> WpT hi/lo
// ---------------------------------------------------------------------------
__global__ __launch_bounds__(256) void prep_all(
    const float* __restrict__ hs,
    const float* __restrict__ attn_w,
    const float* __restrict__ proj_w,
    unsigned short* __restrict__ Ahi, unsigned short* __restrict__ Alo,
    unsigned short* __restrict__ WqThi, unsigned short* __restrict__ WqTlo,
    unsigned short* __restrict__ WpThi, unsigned short* __restrict__ WpTlo)
{
    __shared__ float Ws[64][68];
    const int bid = blockIdx.x;
    const int t   = threadIdx.x;

    if (bid < 2048) {   // ---- elementwise A split
        const size_t i = ((size_t)bid * 256 + t) * 8;
        float4 a = *(const float4*)(hs + i);
        float4 b = *(const float4*)(hs + i + 4);
        float xs[8] = {a.x, a.y, a.z, a.w, b.x, b.y, b.z, b.w};
        short8 h, l;
#pragma unroll
        for (int e = 0; e < 8; e++) {
            unsigned short hh, ll;
            split2(xs[e], hh, ll);
            h[e] = (short)hh; l[e] = (short)ll;
        }
        *(short8*)&Ahi[i] = h;
        *(short8*)&Alo[i] = l;
        return;
    }

    // ---- weight transpose+split sections
    const float* W; unsigned short *Thi, *Tlo; int N, n0, k0;
    if (bid < 2816) {
        const int s = bid - 2048;            // 0..767 = 48 x 16
        W = attn_w; Thi = WqThi; Tlo = WqTlo; N = N_QKV;
        n0 = (s % 48) * 64; k0 = (s / 48) * 64;
    } else {
        const int s = bid - 2816;            // 0..255 = 16 x 16
        W = proj_w; Thi = WpThi; Tlo = WpTlo; N = D_;
        n0 = (s % 16) * 64; k0 = (s / 16) * 64;
    }
    {
        const int kl = t >> 4, nl = (t & 15) * 4;
        const float* src = W + (size_t)(k0 + kl) * N + n0 + nl;
#pragma unroll
        for (int g = 0; g < 4; g++)
            *(float4*)&Ws[kl + g * 16][nl] = *(const float4*)(src + (size_t)g * 16 * N);
    }
    __syncthreads();
    {
        const int nl = t >> 2, ks = (t & 3) * 16;
        short8 h0, h1, l0, l1;
#pragma unroll
        for (int j = 0; j < 8; j++) {
            unsigned short hh, ll;
            split2(Ws[ks + j][nl], hh, ll);
            h0[j] = (short)hh; l0[j] = (short)ll;
        }
#pragma unroll
        for (int j = 0; j < 8; j++) {
            unsigned short hh, ll;
            split2(Ws[ks + 8 + j][nl], hh, ll);
            h1[j] = (short)hh; l1[j] = (short)ll;
        }
        unsigned short* dh = Thi + (size_t)(n0 + nl) * D_ + k0 + ks;
        unsigned short* dl = Tlo + (size_t)(n0 + nl) * D_ + k0 + ks;
        *(short8*)dh = h0; *(short8*)(dh + 8) = h1;
        *(short8*)dl = l0; *(short8*)(dl + 8) = l1;
    }
}

// ---------------------------------------------------------------------------
// QKV GEMM v2: m97 structure, 128x128 tile, single 32KB buffer, fully-DMA
// staging, zero K-loop VALU. NEW: chunk XOR-swizzle (rule #21 both-sides):
// LDS row r, 16B-chunk c holds global chunk c^(r&3); DMA source column is
// inverse-swizzled, fragment reads XOR quad^(lm&3). Turns the 8-way
// stride-64B read conflict into 4-way.
// ---------------------------------------------------------------------------
__global__ __launch_bounds__(256) void gemm_qkv(
    const unsigned short* __restrict__ Ahi, const unsigned short* __restrict__ Alo,
    const unsigned short* __restrict__ BThi, const unsigned short* __restrict__ BTlo,
    const float* __restrict__ bias,
    unsigned short* __restrict__ Qhi, unsigned short* __restrict__ Qlo,
    unsigned short* __restrict__ Khi, unsigned short* __restrict__ Klo,
    unsigned short* __restrict__ vThi, unsigned short* __restrict__ vTlo)
{
    __shared__ unsigned short sAh[128 * 32], sAl[128 * 32];
    __shared__ unsigned short sBh[128 * 32], sBl[128 * 32];   // 32 KB

    const int t    = threadIdx.x;
    const int m0   = blockIdx.y * 128, n0 = blockIdx.x * 128;
    const int lane = t & 63, wave = t >> 6;
    const int lm   = lane & 15, quad = lane >> 4;
    const int wm   = (wave >> 1) * 64, wn = (wave & 1) * 64;

    // staging: thread covers LDS rows {wave*32+(lane>>2), +16}, chunk lane&3.
    // source column inverse-swizzled so linear DMA lands swizzled.
    const int lrow = lane >> 2;
    const int lcol = ((lane & 3) ^ (lrow & 3)) * 8;   // involution (+16 rows: same &3)
    const unsigned short* gAh = Ahi + (size_t)(m0 + wave * 32 + lrow) * D_ + lcol;
    const unsigned short* gAl = Alo + (size_t)(m0 + wave * 32 + lrow) * D_ + lcol;
    const unsigned short* gBh = BThi + (size_t)(n0 + wave * 32 + lrow) * D_ + lcol;
    const unsigned short* gBl = BTlo + (size_t)(n0 + wave * 32 + lrow) * D_ + lcol;
    const int ldst = wave * 1024 + lane * 8;   // u16 dest (= base + lane*16B)
    const int rsw  = lm & 3;                   // read-side chunk XOR

    floatx4 acc[4][4];
#pragma unroll
    for (int i = 0; i < 4; i++)
#pragma unroll
        for (int j = 0; j < 4; j++)
#pragma unroll
            for (int r = 0; r < 4; r++) acc[i][j][r] = 0.f;

    for (int k0 = 0; k0 < D_; k0 += 32) {
        __syncthreads();   // readers of previous tile done
        dma16(gAh + k0, &sAh[ldst]);
        dma16(gAh + (size_t)16 * D_ + k0, &sAh[ldst + 512]);
        dma16(gAl + k0, &sAl[ldst]);
        dma16(gAl + (size_t)16 * D_ + k0, &sAl[ldst + 512]);
        dma16(gBh + k0, &sBh[ldst]);
        dma16(gBh + (size_t)16 * D_ + k0, &sBh[ldst + 512]);
        dma16(gBl + k0, &sBl[ldst]);
        dma16(gBl + (size_t)16 * D_ + k0, &sBl[ldst + 512]);
        __syncthreads();   // staged (compiler drains vmcnt(0) here)

        short8 bhf[4], blf[4];
#pragma unroll
        for (int nb = 0; nb < 4; nb++) {
            const int r = wn + nb * 16 + lm;
            const int coff = ((quad ^ rsw) * 8);
            bhf[nb] = *(const short8*)&sBh[r * 32 + coff];
            blf[nb] = *(const short8*)&sBl[r * 32 + coff];
        }
#pragma unroll
        for (int mb = 0; mb < 4; mb++) {
            const int r = wm + mb * 16 + lm;
            const int coff = ((quad ^ rsw) * 8);
            short8 ah = *(const short8*)&sAh[r * 32 + coff];
            short8 al = *(const short8*)&sAl[r * 32 + coff];
#pragma unroll
            for (int nb = 0; nb < 4; nb++) {
                acc[mb][nb] = __builtin_amdgcn_mfma_f32_16x16x32_bf16(ah, bhf[nb], acc[mb][nb], 0, 0, 0);
                acc[mb][nb] = __builtin_amdgcn_mfma_f32_16x16x32_bf16(al, bhf[nb], acc[mb][nb], 0, 0, 0);
                acc[mb][nb] = __builtin_amdgcn_mfma_f32_16x16x32_bf16(ah, blf[nb], acc[mb][nb], 0, 0, 0);
            }
        }
    }

    const int nmode = n0 >> 10;
    if (nmode == 0) {
#pragma unroll
        for (int nb = 0; nb < 4; nb++) {
            const int c = n0 + wn + nb * 16 + lm;
            const float bv = bias[c];
#pragma unroll
            for (int mb = 0; mb < 4; mb++) {
                const int rowb = m0 + wm + mb * 16 + quad * 4;
#pragma unroll
                for (int r = 0; r < 4; r++) {
                    unsigned short hh, ll;
                    split2((acc[mb][nb][r] + bv) * LOG2E_8, hh, ll);
                    Qhi[(size_t)(rowb + r) * D_ + c] = hh;
                    Qlo[(size_t)(rowb + r) * D_ + c] = ll;
                }
            }
        }
    } else if (nmode == 1) {
#pragma unroll
        for (int nb = 0; nb < 4; nb++) {
            const int c = n0 + wn + nb * 16 + lm;
            const float bv = bias[c];
            const int cq = c - 1024;
#pragma unroll
            for (int mb = 0; mb < 4; mb++) {
                const int rowb = m0 + wm + mb * 16 + quad * 4;
#pragma unroll
                for (int r = 0; r < 4; r++) {
                    unsigned short hh, ll;
                    split2(acc[mb][nb][r] + bv, hh, ll);
                    Khi[(size_t)(rowb + r) * D_ + cq] = hh;
                    Klo[(size_t)(rowb + r) * D_ + cq] = ll;
                }
            }
        }
    } else {
#pragma unroll
        for (int nb = 0; nb < 4; nb++) {
            const int c = n0 + wn + nb * 16 + lm;
            const float bv = bias[c];
            const int cq = c - 2048;
            const int hh_ = cq >> 6, dd = cq & 63;
#pragma unroll
            for (int mb = 0; mb < 4; mb++) {
                const int rowb = m0 + wm + mb * 16 + quad * 4;
                const int bb = rowb >> 11, ss = rowb & 2047;
                unsigned short hv[4], lv[4];
#pragma unroll
                for (int r = 0; r < 4; r++)
                    split2(acc[mb][nb][r] + bv, hv[r], lv[r]);
                const size_t idx = ((size_t)((bb * 16 + hh_) * 64 + dd)) * S_ + ss;
                *(uint2*)&vThi[idx] = make_uint2((unsigned)hv[0] | ((unsigned)hv[1] << 16),
                                                 (unsigned)hv[2] | ((unsigned)hv[3] << 16));
                *(uint2*)&vTlo[idx] = make_uint2((unsigned)lv[0] | ((unsigned)lv[1] << 16),
                                                 (unsigned)lv[2] | ((unsigned)lv[3] << 16));
            }
        }
    }
}

// ---------------------------------------------------------------------------
// Proj GEMM v2 (R11-verified): 64x64 tiles, BK=64, both-sides XOR swizzle,
// XCD-chunk block swizzle, 1024 blocks = 4/CU, 32 KB LDS.
// ---------------------------------------------------------------------------
__global__ __launch_bounds__(256) void gemm_out(
    const unsigned short* __restrict__ Ahi, const unsigned short* __restrict__ Alo,
    const unsigned short* __restrict__ BThi, const unsigned short* __restrict__ BTlo,
    const float* __restrict__ bias, float* __restrict__ C)
{
    __shared__ unsigned short sAh[64 * 64], sAl[64 * 64];
    __shared__ unsigned short sBh[64 * 64], sBl[64 * 64];   // 32 KB

    const int t   = threadIdx.x;
    const int lid = blockIdx.x;                        // 0..1023
    const int swz = (lid & 7) * 128 + (lid >> 3);      // XCD-chunk, bijective
    const int bx  = swz & 15, by = swz >> 4;
    const int m0  = by * 64, n0 = bx * 64;
    const int lane = t & 63, wave = t >> 6;
    const int lm   = lane & 15, quad = lane >> 4;

    // staging: thread t, chunk c in {0,1}: LDS row (t>>3)+32c, colseg t&7;
    // global colseg inverse-swizzled so linear DMA lands swizzled.
    const int r0   = t >> 3;                  // 0..31
    const int gseg = (t & 7) ^ (r0 & 7);      // involution ((r0+32)&7 == r0&7)
    const unsigned short* gAh = Ahi + (size_t)(m0 + r0) * D_ + gseg * 8;
    const unsigned short* gAl = Alo + (size_t)(m0 + r0) * D_ + gseg * 8;
    const unsigned short* gBh = BThi + (size_t)(n0 + r0) * D_ + gseg * 8;
    const unsigned short* gBl = BTlo + (size_t)(n0 + r0) * D_ + gseg * 8;
    const int ld0  = t * 8;                   // chunk0 dest; chunk1 at +2048
    const int swzr = lm & 7;                  // read-side chunk XOR

    floatx4 acc[4];
#pragma unroll
    for (int j = 0; j < 4; j++)
#pragma unroll
        for (int r = 0; r < 4; r++) acc[j][r] = 0.f;

    for (int k0 = 0; k0 < D_; k0 += 64) {
        __syncthreads();
        dma16(gAh + k0, &sAh[ld0]);
        dma16(gAh + (size_t)32 * D_ + k0, &sAh[ld0 + 2048]);
        dma16(gAl + k0, &sAl[ld0]);
        dma16(gAl + (size_t)32 * D_ + k0, &sAl[ld0 + 2048]);
        dma16(gBh + k0, &sBh[ld0]);
        dma16(gBh + (size_t)32 * D_ + k0, &sBh[ld0 + 2048]);
        dma16(gBl + k0, &sBl[ld0]);
        dma16(gBl + (size_t)32 * D_ + k0, &sBl[ld0 + 2048]);
        __syncthreads();

#pragma unroll
        for (int ks = 0; ks < 2; ks++) {
            const int arow = (wave * 16 + lm) * 64 + (((ks * 4 + quad) ^ swzr) * 8);
            short8 ah = *(const short8*)&sAh[arow];
            short8 al = *(const short8*)&sAl[arow];
#pragma unroll
            for (int nb = 0; nb < 4; nb++) {
                const int brow = (nb * 16 + lm) * 64 + (((ks * 4 + quad) ^ swzr) * 8);
                short8 bh = *(const short8*)&sBh[brow];
                short8 bl = *(const short8*)&sBl[brow];
                acc[nb] = __builtin_amdgcn_mfma_f32_16x16x32_bf16(ah, bh, acc[nb], 0, 0, 0);
                acc[nb] = __builtin_amdgcn_mfma_f32_16x16x32_bf16(al, bh, acc[nb], 0, 0, 0);
                acc[nb] = __builtin_amdgcn_mfma_f32_16x16x32_bf16(ah, bl, acc[nb], 0, 0, 0);
            }
        }
    }

#pragma unroll
    for (int nb = 0; nb < 4; nb++) {
        const int col = n0 + nb * 16 + lm;
        const float bv = bias[col];
#pragma unroll
        for (int r = 0; r < 4; r++) {
            const int row = m0 + wave * 16 + quad * 4 + r;
            C[(size_t)row * D_ + col] = acc[nb][r] + bv;
        }
    }
}

// ---------------------------------------------------------------------------
// MFMA flash attention v7 (R11-verified): 128-row Q super-tile, 8 waves,
// DMA-staged XOR-swizzled K/V, XCD-chunked (b,h) mapping, exp2 softmax.
// ---------------------------------------------------------------------------
#define PSP 72   // P row stride (64 data + 8 pad)

__global__ __launch_bounds__(512, 4) void flash_attn_mfma(
    unsigned short* QAhi, unsigned short* QAlo,   // Q in, attn out (aliased)
    const unsigned short* __restrict__ Khi, const unsigned short* __restrict__ Klo,
    const unsigned short* __restrict__ vThi, const unsigned short* __restrict__ vTlo)
{
    __shared__ unsigned short KhS[64 * 64], KlS[64 * 64];   // swizzled, 8 KB ea
    __shared__ unsigned short VhS[64 * 64], VlS[64 * 64];   // V^T tile [d][s]
    __shared__ unsigned short PhS[128 * PSP], PlS[128 * PSP]; // 68 KB total

    const int t    = threadIdx.x;           // 0..511
    // XCD-chunked remap: lid%8 = XCD; each XCD gets 4 bh
    const int lid  = blockIdx.x + 16 * blockIdx.y;   // 0..511
    const int bh   = (lid & 7) * 4 + ((lid >> 3) & 3);
    const int pj   = lid >> 5;              // 0..15
    const int b    = bh >> 4, h = bh & 15;
    const int lane = t & 63, w = t >> 6;    // 8 waves
    const int lm   = lane & 15, quad = lane >> 4;

    const int qt = (bh & 1) ? (15 - pj) : pj;   // balance pairing
    const int q0 = qt * 128;
    const int ntiles = 2 * qt + 2;
    const int wdiag = (q0 >> 6) + (w >> 2);     // waves 0-3: 2qt; 4-7: 2qt+1

    // staging geometry (rule #21): linear DMA dest + inverse-swizzled source
    const int r0  = t >> 3;                       // 0..63
    const int seg = (t & 7) ^ (r0 & 7);           // involution
    const unsigned short* gKh = Khi + (size_t)(b * S_ + r0) * D_ + h * HD + 8 * seg;
    const unsigned short* gKl = Klo + (size_t)(b * S_ + r0) * D_ + h * HD + 8 * seg;
    const unsigned short* gVh = vThi + ((size_t)((b * 16 + h) * 64 + r0)) * S_ + 8 * seg;
    const unsigned short* gVl = vTlo + ((size_t)((b * 16 + h) * 64 + r0)) * S_ + 8 * seg;
    const int ld0 = t * 8;                        // u16 dest (= base + t*16B)
    const int swzr = (lm & 7) << 3;               // read-side XOR (u16 units)

    // Q fragments (A-layout rows q0+16w+lm), pre-scaled by log2e/8
    short8 qh[2], ql[2];
    {
        const size_t qoff = (size_t)(b * S_ + q0 + 16 * w + lm) * D_ + h * HD + quad * 8;
        qh[0] = *(const short8*)&QAhi[qoff];
        qh[1] = *(const short8*)&QAhi[qoff + 32];
        ql[0] = *(const short8*)&QAlo[qoff];
        ql[1] = *(const short8*)&QAlo[qoff + 32];
    }

    float lsum[4] = {0.f, 0.f, 0.f, 0.f};
    floatx4 o[4];
#pragma unroll
    for (int nb = 0; nb < 4; nb++)
#pragma unroll
        for (int r = 0; r < 4; r++) o[nb][r] = 0.f;

    for (int kt = 0; kt < ntiles; kt++) {
        __syncthreads();   // all waves done reading previous tile
        {
            const size_t ko = (size_t)(kt * 64) * D_;
            const int vo = kt * 64;
            dma16(gKh + ko, &KhS[ld0]);
            dma16(gKl + ko, &KlS[ld0]);
            dma16(gVh + vo, &VhS[ld0]);
            dma16(gVl + vo, &VlS[ld0]);
        }
        __syncthreads();   // DMA drained (vmcnt0 at barrier)

        if (kt <= wdiag) {   // wave-uniform causal skip
            // ---- S = Q K^T (3-MFMA split), swizzled K reads
            floatx4 sa[4];
#pragma unroll
            for (int nb = 0; nb < 4; nb++)
#pragma unroll
                for (int r = 0; r < 4; r++) sa[nb][r] = 0.f;
            __builtin_amdgcn_s_setprio(1);
#pragma unroll
            for (int s = 0; s < 2; s++) {
#pragma unroll
                for (int nb = 0; nb < 4; nb++) {
                    const int ka = (nb * 16 + lm) * 64 + ((s * 32 + quad * 8) ^ swzr);
                    short8 kh = *(const short8*)&KhS[ka];
                    short8 kl = *(const short8*)&KlS[ka];
                    sa[nb] = __builtin_amdgcn_mfma_f32_16x16x32_bf16(qh[s], kh, sa[nb], 0, 0, 0);
                    sa[nb] = __builtin_amdgcn_mfma_f32_16x16x32_bf16(ql[s], kh, sa[nb], 0, 0, 0);
                    sa[nb] = __builtin_amdgcn_mfma_f32_16x16x32_bf16(qh[s], kl, sa[nb], 0, 0, 0);
                }
            }
            __builtin_amdgcn_s_setprio(0);

            // ---- softmax-lite (no shift); mask only on the diag tile
            const bool diag = (kt == wdiag);
            const int kbase = kt * 64;
#pragma unroll
            for (int r = 0; r < 4; r++) {
                const int qabs = q0 + 16 * w + 4 * quad + r;
                const int rloc = 16 * w + 4 * quad + r;
#pragma unroll
                for (int nb = 0; nb < 4; nb++) {
                    float p = exp2f(sa[nb][r]);   // native v_exp_f32
                    if (diag && (kbase + 16 * nb + lm > qabs)) p = 0.f;
                    lsum[r] += p;
                    unsigned short hh, ll;
                    split2(p, hh, ll);
                    PhS[rloc * PSP + 16 * nb + lm] = hh;
                    PlS[rloc * PSP + 16 * nb + lm] = ll;
                }
            }

            // ---- O += P V (same-wave P rows; swizzled V reads)
            __builtin_amdgcn_s_setprio(1);
#pragma unroll
            for (int ks = 0; ks < 2; ks++) {
                short8 pf = *(const short8*)&PhS[(16 * w + lm) * PSP + ks * 32 + quad * 8];
                short8 pg = *(const short8*)&PlS[(16 * w + lm) * PSP + ks * 32 + quad * 8];
#pragma unroll
                for (int nb = 0; nb < 4; nb++) {
                    const int va = (nb * 16 + lm) * 64 + ((ks * 32 + quad * 8) ^ swzr);
                    short8 vhf = *(const short8*)&VhS[va];
                    short8 vlf = *(const short8*)&VlS[va];
                    o[nb] = __builtin_amdgcn_mfma_f32_16x16x32_bf16(pf, vhf, o[nb], 0, 0, 0);
                    o[nb] = __builtin_amdgcn_mfma_f32_16x16x32_bf16(pg, vhf, o[nb], 0, 0, 0);
                    o[nb] = __builtin_amdgcn_mfma_f32_16x16x32_bf16(pf, vlf, o[nb], 0, 0, 0);
                }
            }
            __builtin_amdgcn_s_setprio(0);
        }
    }

    // epilogue: reduce l, normalize, write attn PRE-SPLIT into Q buffers
#pragma unroll
    for (int r = 0; r < 4; r++) {
        float l = lsum[r];
        l += __shfl_xor(l, 1);
        l += __shfl_xor(l, 2);
        l += __shfl_xor(l, 4);
        l += __shfl_xor(l, 8);
        const float inv = 1.f / l;
        const size_t rowoff =
            (size_t)(b * S_ + q0 + 16 * w + 4 * quad + r) * D_ + h * HD + lm;
#pragma unroll
        for (int nb = 0; nb < 4; nb++) {
            unsigned short hh, ll;
            split2(o[nb][r] * inv, hh, ll);
            QAhi[rowoff + 16 * nb] = hh;
            QAlo[rowoff + 16 * nb] = ll;
        }
    }
}

// ---------------------------------------------------------------------------
extern "C" void kernel_launch(void* const* d_in, const int* in_sizes, int n_in,
                              void* d_out, int out_size, void* d_ws, size_t ws_size,
                              hipStream_t stream)
{
    const float* hs     = (const float*)d_in[0];
    const float* attn_w = (const float*)d_in[1];
    const float* attn_b = (const float*)d_in[2];
    const float* proj_w = (const float*)d_in[3];
    const float* proj_b = (const float*)d_in[4];
    float* outp = (float*)d_out;

    const size_t QE = (size_t)M_ * D_;          // 4,194,304
    const size_t WQ = (size_t)D_ * N_QKV;       // 3,145,728
    unsigned short* Qhi   = (unsigned short*)d_ws;       // also attn hi
    unsigned short* Qlo   = Qhi + QE;                    // also attn lo
    unsigned short* Khi   = Qlo + QE;
    unsigned short* Klo   = Khi + QE;
    unsigned short* vThi  = Klo + QE;
    unsigned short* vTlo  = vThi + QE;
    unsigned short* WqThi = vTlo + QE;
    unsigned short* WqTlo = WqThi + WQ;
    unsigned short* WpThi = WqTlo + WQ;
    unsigned short* WpTlo = WpThi + (size_t)D_ * D_;
    unsigned short* Ahi   = WpTlo + (size_t)D_ * D_;     // hs pre-split
    unsigned short* Alo   = Ahi + QE;                    // total = 80 MB

    dim3 blk(256);
    prep_all<<<dim3(3072), blk, 0, stream>>>(
        hs, attn_w, proj_w, Ahi, Alo, WqThi, WqTlo, WpThi, WpTlo);
    gemm_qkv<<<dim3(N_QKV / 128, M_ / 128), blk, 0, stream>>>(
        Ahi, Alo, WqThi, WqTlo, attn_b, Qhi, Qlo, Khi, Klo, vThi, vTlo);
    flash_attn_mfma<<<dim3(16, B_ * H_), dim3(512), 0, stream>>>(
        Qhi, Qlo, Khi, Klo, vThi, vTlo);
    gemm_out<<<dim3(1024), blk, 0, stream>>>(
        Qhi, Qlo, WpThi, WpTlo, proj_b, outp);
}